// Round 2
// baseline (5174.712 us; speedup 1.0000x reference)
//
#include <hip/hip_runtime.h>
#include <cstdint>

#define T_DIM 4
#define B_DIM 8
#define C_DIM 512
#define N_DIM 576
#define CV_DIM 2048
#define TB_DIM 32
#define NW 9              // u64 words per row of N=576

typedef unsigned long long u64;
typedef unsigned char u8;

// ---------------- Stage 1: LIF over (x + pos) -> bit-packed spikes ----------------
__global__ __launch_bounds__(576) void lif_x_pack(const float* __restrict__ x,
                                                  const float* __restrict__ pos,
                                                  u64* __restrict__ sxb) {
    const int bc = blockIdx.x;             // b*512 + c
    const int c = bc & (C_DIM - 1);
    const int n = threadIdx.x;             // 0..575
    const int lane = n & 63, wv = n >> 6;
    const float p = pos[c * N_DIM + n];
    const size_t BCN = (size_t)B_DIM * C_DIM * N_DIM;
    float mem = 0.f, s = 0.f;
    for (int t = 0; t < T_DIM; ++t) {
        float xt = x[t * BCN + (size_t)bc * N_DIM + n] + p;
        mem = mem * 0.25f * (1.f - s) + xt;     // contraction harmless: (1-s) in {0,1}
        s = (mem > 0.5f) ? 1.f : 0.f;
        u64 m = __ballot(s > 0.f);
        if (lane == 0) sxb[((size_t)t * (B_DIM * C_DIM) + bc) * NW + wv] = m;
    }
}

// ---------------- Fused q/k/v GEMM (fp32 W x spike bits) + scale/bias + LIF + pack ----------------
#define GBM 64
#define GBN 64
#define GBK 32
#define ASTR 68

__global__ __launch_bounds__(256) void gemm_qkv_fused(const float* __restrict__ W,
        const u64* __restrict__ sxb,
        const float* __restrict__ scale, const float* __restrict__ bias,
        u64* __restrict__ qkvb, int M, int K, int row_off) {
    __shared__ float As[GBK][ASTR];            // 8.7 KB
    __shared__ float Bs[T_DIM][GBK][GBN];      // 32 KB
    __shared__ u8 su8[GBM][GBN];               // 4 KB

    const int b = blockIdx.z;
    const int m0 = blockIdx.x * GBM;
    const int wq = blockIdx.y;                 // n-word index (n0 = wq*64)
    const int tid = threadIdx.x;
    const int wave = tid >> 6, lane = tid & 63;
    const int r0 = (tid >> 4) * 4, c0 = (tid & 15) * 4;

    float acc[T_DIM][4][4];
    #pragma unroll
    for (int t = 0; t < T_DIM; ++t)
        #pragma unroll
        for (int i = 0; i < 4; ++i)
            #pragma unroll
            for (int j = 0; j < 4; ++j) acc[t][i][j] = 0.f;

    for (int k0 = 0; k0 < K; k0 += GBK) {
        // A tile 64x32 -> LDS transposed
        #pragma unroll
        for (int rep = 0; rep < 2; ++rep) {
            int lin = rep * 256 + tid;
            int row = lin >> 3, g = (lin & 7) * 4;
            const float4 a4 = *reinterpret_cast<const float4*>(W + (size_t)(m0 + row) * K + k0 + g);
            As[g + 0][row] = a4.x;
            As[g + 1][row] = a4.y;
            As[g + 2][row] = a4.z;
            As[g + 3][row] = a4.w;
        }
        // B tiles: expand spike bits for 4 t's; wave w handles t=w
        {
            const u64* sp = sxb + ((size_t)wave * (B_DIM * C_DIM) + (size_t)b * C_DIM + k0) * NW + wq;
            #pragma unroll
            for (int kk = 0; kk < GBK; ++kk) {
                u64 w = sp[(size_t)kk * NW];
                Bs[wave][kk][lane] = (float)((w >> lane) & 1ULL);
            }
        }
        __syncthreads();
        #pragma unroll
        for (int kk = 0; kk < GBK; ++kk) {
            const float4 a4 = *reinterpret_cast<const float4*>(&As[kk][r0]);
            float av[4] = {a4.x, a4.y, a4.z, a4.w};
            #pragma unroll
            for (int t = 0; t < T_DIM; ++t) {
                const float4 b4 = *reinterpret_cast<const float4*>(&Bs[t][kk][c0]);
                float bv[4] = {b4.x, b4.y, b4.z, b4.w};
                #pragma unroll
                for (int i = 0; i < 4; ++i)
                    #pragma unroll
                    for (int j = 0; j < 4; ++j)
                        acc[t][i][j] += av[i] * bv[j];   // bv in {0,1}: contraction exact
            }
        }
        __syncthreads();
    }

    // epilogue: conv_bn scale/bias (two-rounding like ref) + LIF across t + bit-pack
    float sc[4], bi[4];
    #pragma unroll
    for (int i = 0; i < 4; ++i) { sc[i] = scale[m0 + r0 + i]; bi[i] = bias[m0 + r0 + i]; }
    float mem[4][4], spk[4][4];
    #pragma unroll
    for (int i = 0; i < 4; ++i)
        #pragma unroll
        for (int j = 0; j < 4; ++j) { mem[i][j] = 0.f; spk[i][j] = 0.f; }

    for (int t = 0; t < T_DIM; ++t) {
        #pragma unroll
        for (int i = 0; i < 4; ++i)
            #pragma unroll
            for (int j = 0; j < 4; ++j) {
                float y = __fadd_rn(__fmul_rn(acc[t][i][j], sc[i]), bi[i]);
                mem[i][j] = mem[i][j] * 0.25f * (1.f - spk[i][j]) + y;
                float sn = (mem[i][j] > 0.5f) ? 1.f : 0.f;
                spk[i][j] = sn;
                su8[r0 + i][c0 + j] = (u8)sn;
            }
        __syncthreads();
        if (tid < GBM) {
            u64 word = 0;
            #pragma unroll
            for (int w8 = 0; w8 < 8; ++w8) {
                u64 v = *reinterpret_cast<const u64*>(&su8[tid][w8 * 8]);
                word |= ((v * 0x0102040810204080ULL) >> 56) << (w8 * 8);
            }
            qkvb[((size_t)t * (B_DIM * 3072) + (size_t)b * 3072 + row_off + m0 + tid) * NW + wq] = word;
        }
        __syncthreads();
    }
}

// ---------------- Stage 4a: kv[d,e] = popcount over n of k&v (exact integers) ----------------
__global__ __launch_bounds__(256) void kv_pop_kernel(const u64* __restrict__ bits,
                                                     float* __restrict__ kv) {
    int tbh = blockIdx.x;               // 0..255 : tb*8 + h
    int tb = tbh >> 3, h = tbh & 7;
    int e = threadIdx.x;                // 0..255
    __shared__ u64 kb[64][NW];
    const u64* kbase = bits + ((size_t)tb * 3072 + 512 + h * 64) * NW;
    const u64* vbase = bits + ((size_t)tb * 3072 + 1024 + h * 256) * NW;
    for (int i = threadIdx.x; i < 576; i += 256) kb[i / 9][i % 9] = kbase[i];
    __syncthreads();
    u64 vr[NW];
    #pragma unroll
    for (int w = 0; w < NW; ++w) vr[w] = vbase[(size_t)e * NW + w];
    float* kvp = kv + (size_t)tbh * 16384 + e;
    #pragma unroll 4
    for (int d = 0; d < 64; ++d) {
        int scnt = 0;
        #pragma unroll
        for (int w = 0; w < NW; ++w) scnt += __popcll(kb[d][w] & vr[w]);
        kvp[(size_t)d * 256] = (float)scnt;
    }
}

// ---------------- Stage 4b+5: o = 0.25 * q@kv (exact), fused LIF + bit-pack ----------------
#define ECH 16
__global__ __launch_bounds__(576) void o_attn_fused(const u64* __restrict__ qkvb,
                                                    const float* __restrict__ kv,
                                                    u64* __restrict__ sob) {
    const int blk = blockIdx.x;            // ((b*8+h)*16 + ec)
    const int ec = blk & 15, h = (blk >> 4) & 7, b = blk >> 7;
    const int e0 = ec * ECH;
    const int n = threadIdx.x, lane = n & 63, nw = n >> 6;
    __shared__ float kvs[T_DIM][64][ECH];  // 16 KB
    __shared__ u64 qb[T_DIM][576];         // 18 KB

    for (int i = n; i < T_DIM * 64 * ECH; i += 576) {
        int t = i >> 10, d = (i >> 4) & 63, e = i & 15;
        kvs[t][d][e] = kv[(((size_t)(t * 8 + b) * 8 + h) * 64 + d) * 256 + e0 + e];
    }
    #pragma unroll
    for (int t = 0; t < T_DIM; ++t)
        qb[t][n] = qkvb[((size_t)(t * 8 + b) * 3072 + h * 64) * NW + n];
    __syncthreads();

    float mem[ECH], spk[ECH];
    #pragma unroll
    for (int e = 0; e < ECH; ++e) { mem[e] = 0.f; spk[e] = 0.f; }

    for (int t = 0; t < T_DIM; ++t) {
        float bitf[64];
        #pragma unroll
        for (int d = 0; d < 64; ++d)
            bitf[d] = (float)((qb[t][d * 9 + nw] >> lane) & 1ULL);
        #pragma unroll
        for (int eg = 0; eg < ECH; eg += 4) {
            float a0 = 0.f, a1 = 0.f, a2 = 0.f, a3 = 0.f;
            #pragma unroll
            for (int d = 0; d < 64; ++d) {
                const float4 kq = *reinterpret_cast<const float4*>(&kvs[t][d][eg]);
                a0 += bitf[d] * kq.x;
                a1 += bitf[d] * kq.y;
                a2 += bitf[d] * kq.z;
                a3 += bitf[d] * kq.w;
            }
            float av[4] = {a0, a1, a2, a3};
            #pragma unroll
            for (int j = 0; j < 4; ++j) {
                int e = eg + j;
                mem[e] = mem[e] * 0.25f * (1.f - spk[e]) + av[j] * 0.25f;  // all exact ints*0.25
                float sn = (mem[e] > 0.5f) ? 1.f : 0.f;
                spk[e] = sn;
                u64 msk = __ballot(sn > 0.f);
                if (lane == 0)
                    sob[((size_t)(t * 8 + b) * CV_DIM + h * 256 + e0 + e) * NW + nw] = msk;
            }
        }
    }
}

// ---------------- Output projection: fp32 W x spike bits + scale/bias ----------------
__global__ __launch_bounds__(256) void gemm_p(const float* __restrict__ W,
        const u64* __restrict__ sob,
        const float* __restrict__ scale, const float* __restrict__ bias,
        float* __restrict__ out) {
    __shared__ float As[GBK][ASTR];
    __shared__ float Bs[GBK][GBN];
    const int tb = blockIdx.z;
    const int m0 = blockIdx.x * GBM;
    const int wq = blockIdx.y;
    const int n0 = wq * 64;
    const int tid = threadIdx.x;
    const int wave = tid >> 6, lane = tid & 63;
    const int r0 = (tid >> 4) * 4, c0 = (tid & 15) * 4;

    float acc[4][4];
    #pragma unroll
    for (int i = 0; i < 4; ++i)
        #pragma unroll
        for (int j = 0; j < 4; ++j) acc[i][j] = 0.f;

    const u64* sp = sob + (size_t)tb * CV_DIM * NW + wq;
    for (int k0 = 0; k0 < CV_DIM; k0 += GBK) {
        #pragma unroll
        for (int rep = 0; rep < 2; ++rep) {
            int lin = rep * 256 + tid;
            int row = lin >> 3, g = (lin & 7) * 4;
            const float4 a4 = *reinterpret_cast<const float4*>(W + (size_t)(m0 + row) * CV_DIM + k0 + g);
            As[g + 0][row] = a4.x;
            As[g + 1][row] = a4.y;
            As[g + 2][row] = a4.z;
            As[g + 3][row] = a4.w;
        }
        #pragma unroll
        for (int q8 = 0; q8 < 8; ++q8) {
            int kk = wave * 8 + q8;
            u64 w = sp[(size_t)(k0 + kk) * NW];
            Bs[kk][lane] = (float)((w >> lane) & 1ULL);
        }
        __syncthreads();
        #pragma unroll
        for (int kk = 0; kk < GBK; ++kk) {
            const float4 a4 = *reinterpret_cast<const float4*>(&As[kk][r0]);
            float av[4] = {a4.x, a4.y, a4.z, a4.w};
            const float4 b4 = *reinterpret_cast<const float4*>(&Bs[kk][c0]);
            float bv[4] = {b4.x, b4.y, b4.z, b4.w};
            #pragma unroll
            for (int i = 0; i < 4; ++i)
                #pragma unroll
                for (int j = 0; j < 4; ++j)
                    acc[i][j] += av[i] * bv[j];
        }
        __syncthreads();
    }
    #pragma unroll
    for (int i = 0; i < 4; ++i) {
        float sc = scale[m0 + r0 + i], bi = bias[m0 + r0 + i];
        float4 r;
        r.x = __fadd_rn(__fmul_rn(acc[i][0], sc), bi);
        r.y = __fadd_rn(__fmul_rn(acc[i][1], sc), bi);
        r.z = __fadd_rn(__fmul_rn(acc[i][2], sc), bi);
        r.w = __fadd_rn(__fmul_rn(acc[i][3], sc), bi);
        *reinterpret_cast<float4*>(out + (size_t)tb * (C_DIM * N_DIM)
                                   + (size_t)(m0 + r0 + i) * N_DIM + n0 + c0) = r;
    }
}

extern "C" void kernel_launch(void* const* d_in, const int* in_sizes, int n_in,
                              void* d_out, int out_size, void* d_ws, size_t ws_size,
                              hipStream_t stream) {
    const float* x    = (const float*)d_in[0];
    const float* pos  = (const float*)d_in[1];
    const float* q_w  = (const float*)d_in[2];
    const float* q_s  = (const float*)d_in[3];
    const float* q_b  = (const float*)d_in[4];
    const float* k_w  = (const float*)d_in[5];
    const float* k_s  = (const float*)d_in[6];
    const float* k_b  = (const float*)d_in[7];
    const float* v_w  = (const float*)d_in[8];
    const float* v_s  = (const float*)d_in[9];
    const float* v_b  = (const float*)d_in[10];
    const float* p_w  = (const float*)d_in[11];
    const float* p_s  = (const float*)d_in[12];
    const float* p_b  = (const float*)d_in[13];
    float* out = (float*)d_out;

    char* ws = (char*)d_ws;
    u64* sxb  = (u64*)ws;                                       // [T][B*512][9]  1,179,648 B
    u64* qkvb = (u64*)(ws + 1179648);                           // [T*B][3072][9] 7,077,888 B
    float* kv = (float*)(ws + 1179648 + 7077888);               // [T*B*8][64][256] 16,777,216 B
    u64* sob  = (u64*)(ws + 1179648 + 7077888 + 16777216);      // [T*B][2048][9] 4,718,592 B
    // total: 29,753,344 B

    // 1) LIF on x+pos -> packed spikes
    lif_x_pack<<<B_DIM * C_DIM, 576, 0, stream>>>(x, pos, sxb);

    // 2) fused q/k/v GEMM + LIF + pack (loops t internally)
    dim3 gq(C_DIM / GBM, NW, B_DIM);    // (8,9,8)
    gemm_qkv_fused<<<gq, 256, 0, stream>>>(q_w, sxb, q_s, q_b, qkvb, C_DIM, C_DIM, 0);
    gemm_qkv_fused<<<gq, 256, 0, stream>>>(k_w, sxb, k_s, k_b, qkvb, C_DIM, C_DIM, 512);
    dim3 gv(CV_DIM / GBM, NW, B_DIM);   // (32,9,8)
    gemm_qkv_fused<<<gv, 256, 0, stream>>>(v_w, sxb, v_s, v_b, qkvb, CV_DIM, C_DIM, 1024);

    // 3) attention: exact popcount kv, then fused o + LIF + pack
    kv_pop_kernel<<<TB_DIM * 8, 256, 0, stream>>>(qkvb, kv);
    o_attn_fused<<<B_DIM * 8 * 16, 576, 0, stream>>>(qkvb, kv, sob);

    // 4) output projection
    dim3 gp(C_DIM / GBM, NW, TB_DIM);   // (8,9,32)
    gemm_p<<<gp, 256, 0, stream>>>(p_w, sob, p_s, p_b, out);
}

// Round 3
// 1521.563 us; speedup vs baseline: 3.4009x; 3.4009x over previous
//
#include <hip/hip_runtime.h>
#include <cstdint>

#define T_DIM 4
#define B_DIM 8
#define C_DIM 512
#define N_DIM 576
#define CV_DIM 2048
#define TB_DIM 32
#define NW 9              // u64 words per row of N=576

typedef unsigned long long u64;
typedef unsigned char u8;

// ---------------- Stage 1: LIF over (x + pos) -> bit-packed spikes ----------------
__global__ __launch_bounds__(576) void lif_x_pack(const float* __restrict__ x,
                                                  const float* __restrict__ pos,
                                                  u64* __restrict__ sxb) {
    const int bc = blockIdx.x;             // b*512 + c
    const int c = bc & (C_DIM - 1);
    const int n = threadIdx.x;             // 0..575
    const int lane = n & 63, wv = n >> 6;
    const float p = pos[c * N_DIM + n];
    const size_t BCN = (size_t)B_DIM * C_DIM * N_DIM;
    float mem = 0.f, s = 0.f;
    for (int t = 0; t < T_DIM; ++t) {
        float xt = x[t * BCN + (size_t)bc * N_DIM + n] + p;
        mem = mem * 0.25f * (1.f - s) + xt;     // contraction harmless: (1-s) in {0,1}
        s = (mem > 0.5f) ? 1.f : 0.f;
        u64 m = __ballot(s > 0.f);
        if (lane == 0) sxb[((size_t)t * (B_DIM * C_DIM) + bc) * NW + wv] = m;
    }
}

// ---------------- Fused q/k/v GEMM (fp32 W x spike bits) + scale/bias + LIF + pack ----------------
#define GBM 64
#define GBN 64
#define GBK 32
#define ASTR 68

__global__ __launch_bounds__(256) void gemm_qkv_fused(const float* __restrict__ W,
        const u64* __restrict__ sxb,
        const float* __restrict__ scale, const float* __restrict__ bias,
        u64* __restrict__ qkvb, int M, int K, int row_off) {
    __shared__ float As[GBK][ASTR];            // 8.7 KB
    __shared__ float Bs[T_DIM][GBK][GBN];      // 32 KB
    __shared__ u8 su8[GBM][GBN];               // 4 KB

    const int b = blockIdx.z;
    const int m0 = blockIdx.x * GBM;
    const int wq = blockIdx.y;                 // n-word index (n0 = wq*64)
    const int tid = threadIdx.x;
    const int wave = tid >> 6, lane = tid & 63;
    const int r0 = (tid >> 4) * 4, c0 = (tid & 15) * 4;

    float acc[T_DIM][4][4];
    #pragma unroll
    for (int t = 0; t < T_DIM; ++t)
        #pragma unroll
        for (int i = 0; i < 4; ++i)
            #pragma unroll
            for (int j = 0; j < 4; ++j) acc[t][i][j] = 0.f;

    for (int k0 = 0; k0 < K; k0 += GBK) {
        // A tile 64x32 -> LDS transposed
        #pragma unroll
        for (int rep = 0; rep < 2; ++rep) {
            int lin = rep * 256 + tid;
            int row = lin >> 3, g = (lin & 7) * 4;
            const float4 a4 = *reinterpret_cast<const float4*>(W + (size_t)(m0 + row) * K + k0 + g);
            As[g + 0][row] = a4.x;
            As[g + 1][row] = a4.y;
            As[g + 2][row] = a4.z;
            As[g + 3][row] = a4.w;
        }
        // B tiles: expand spike bits for 4 t's; wave w handles t=w
        {
            const u64* sp = sxb + ((size_t)wave * (B_DIM * C_DIM) + (size_t)b * C_DIM + k0) * NW + wq;
            #pragma unroll
            for (int kk = 0; kk < GBK; ++kk) {
                u64 w = sp[(size_t)kk * NW];
                Bs[wave][kk][lane] = (float)((w >> lane) & 1ULL);
            }
        }
        __syncthreads();
        #pragma unroll
        for (int kk = 0; kk < GBK; ++kk) {
            const float4 a4 = *reinterpret_cast<const float4*>(&As[kk][r0]);
            float av[4] = {a4.x, a4.y, a4.z, a4.w};
            #pragma unroll
            for (int t = 0; t < T_DIM; ++t) {
                const float4 b4 = *reinterpret_cast<const float4*>(&Bs[t][kk][c0]);
                float bv[4] = {b4.x, b4.y, b4.z, b4.w};
                #pragma unroll
                for (int i = 0; i < 4; ++i)
                    #pragma unroll
                    for (int j = 0; j < 4; ++j)
                        acc[t][i][j] += av[i] * bv[j];   // bv in {0,1}: contraction exact
            }
        }
        __syncthreads();
    }

    // epilogue: conv_bn scale/bias (two-rounding like ref) + LIF across t + bit-pack
    float sc[4], bi[4];
    #pragma unroll
    for (int i = 0; i < 4; ++i) { sc[i] = scale[m0 + r0 + i]; bi[i] = bias[m0 + r0 + i]; }
    float mem[4][4], spk[4][4];
    #pragma unroll
    for (int i = 0; i < 4; ++i)
        #pragma unroll
        for (int j = 0; j < 4; ++j) { mem[i][j] = 0.f; spk[i][j] = 0.f; }

    for (int t = 0; t < T_DIM; ++t) {
        #pragma unroll
        for (int i = 0; i < 4; ++i)
            #pragma unroll
            for (int j = 0; j < 4; ++j) {
                float y = __fadd_rn(__fmul_rn(acc[t][i][j], sc[i]), bi[i]);
                mem[i][j] = mem[i][j] * 0.25f * (1.f - spk[i][j]) + y;
                float sn = (mem[i][j] > 0.5f) ? 1.f : 0.f;
                spk[i][j] = sn;
                su8[r0 + i][c0 + j] = (u8)sn;
            }
        __syncthreads();
        if (tid < GBM) {
            u64 word = 0;
            #pragma unroll
            for (int w8 = 0; w8 < 8; ++w8) {
                u64 v = *reinterpret_cast<const u64*>(&su8[tid][w8 * 8]);
                word |= ((v * 0x0102040810204080ULL) >> 56) << (w8 * 8);
            }
            qkvb[((size_t)t * (B_DIM * 3072) + (size_t)b * 3072 + row_off + m0 + tid) * NW + wq] = word;
        }
        __syncthreads();
    }
}

// ---------------- Stage 4a: kv[d,e] = popcount over n of k&v (exact integers) ----------------
__global__ __launch_bounds__(256) void kv_pop_kernel(const u64* __restrict__ bits,
                                                     float* __restrict__ kv) {
    int tbh = blockIdx.x;               // 0..255 : tb*8 + h
    int tb = tbh >> 3, h = tbh & 7;
    int e = threadIdx.x;                // 0..255
    __shared__ u64 kb[64][NW];
    const u64* kbase = bits + ((size_t)tb * 3072 + 512 + h * 64) * NW;
    const u64* vbase = bits + ((size_t)tb * 3072 + 1024 + h * 256) * NW;
    for (int i = threadIdx.x; i < 576; i += 256) kb[i / 9][i % 9] = kbase[i];
    __syncthreads();
    u64 vr[NW];
    #pragma unroll
    for (int w = 0; w < NW; ++w) vr[w] = vbase[(size_t)e * NW + w];
    float* kvp = kv + (size_t)tbh * 16384 + e;
    #pragma unroll 4
    for (int d = 0; d < 64; ++d) {
        int scnt = 0;
        #pragma unroll
        for (int w = 0; w < NW; ++w) scnt += __popcll(kb[d][w] & vr[w]);
        kvp[(size_t)d * 256] = (float)scnt;
    }
}

// ---------------- Stage 4b+5: o = 0.25 * q@kv (exact), fused LIF + bit-pack ----------------
// v2: q-row bits live in ONE u64 register per thread (no bitf[64] scratch spill).
#define ECH 16
__global__ __launch_bounds__(576) void o_attn_fused(const u64* __restrict__ qkvb,
                                                    const float* __restrict__ kv,
                                                    u64* __restrict__ sob) {
    const int blk = blockIdx.x;            // ((b*8+h)*16 + ec)
    const int ec = blk & 15, h = (blk >> 4) & 7, b = blk >> 7;
    const int e0 = ec * ECH;
    const int n = threadIdx.x, lane = n & 63, nw = n >> 6;
    __shared__ float kvs[T_DIM][64][ECH];  // 16 KB
    __shared__ u64 qb[T_DIM][576];         // 18 KB

    for (int i = n; i < T_DIM * 64 * ECH; i += 576) {
        int t = i >> 10, d = (i >> 4) & 63, e = i & 15;
        kvs[t][d][e] = kv[(((size_t)(t * 8 + b) * 8 + h) * 64 + d) * 256 + e0 + e];
    }
    #pragma unroll
    for (int t = 0; t < T_DIM; ++t)
        qb[t][n] = qkvb[((size_t)(t * 8 + b) * 3072 + h * 64) * NW + n];
    __syncthreads();

    float mem[ECH], spk[ECH];
    #pragma unroll
    for (int e = 0; e < ECH; ++e) { mem[e] = 0.f; spk[e] = 0.f; }

    for (int t = 0; t < T_DIM; ++t) {
        // pack this thread's q-row (bit d = q[n, d]) into one u64 register
        u64 qword = 0;
        #pragma unroll
        for (int d = 0; d < 64; ++d)
            qword |= ((qb[t][d * 9 + nw] >> lane) & 1ULL) << d;

        float acc[ECH];
        #pragma unroll
        for (int e = 0; e < ECH; ++e) acc[e] = 0.f;

        #pragma unroll 8
        for (int d = 0; d < 64; ++d) {
            float f = (float)((qword >> d) & 1ULL);
            const float4 k0 = *reinterpret_cast<const float4*>(&kvs[t][d][0]);
            const float4 k1 = *reinterpret_cast<const float4*>(&kvs[t][d][4]);
            const float4 k2 = *reinterpret_cast<const float4*>(&kvs[t][d][8]);
            const float4 k3 = *reinterpret_cast<const float4*>(&kvs[t][d][12]);
            acc[0]  += f * k0.x; acc[1]  += f * k0.y; acc[2]  += f * k0.z; acc[3]  += f * k0.w;
            acc[4]  += f * k1.x; acc[5]  += f * k1.y; acc[6]  += f * k1.z; acc[7]  += f * k1.w;
            acc[8]  += f * k2.x; acc[9]  += f * k2.y; acc[10] += f * k2.z; acc[11] += f * k2.w;
            acc[12] += f * k3.x; acc[13] += f * k3.y; acc[14] += f * k3.z; acc[15] += f * k3.w;
        }

        #pragma unroll
        for (int e = 0; e < ECH; ++e) {
            mem[e] = mem[e] * 0.25f * (1.f - spk[e]) + acc[e] * 0.25f;  // exact quarter-ints
            float sn = (mem[e] > 0.5f) ? 1.f : 0.f;
            spk[e] = sn;
            u64 msk = __ballot(sn > 0.f);
            if (lane == 0)
                sob[((size_t)(t * 8 + b) * CV_DIM + h * 256 + e0 + e) * NW + nw] = msk;
        }
    }
}

// ---------------- Output projection: fp32 W x spike bits + scale/bias ----------------
__global__ __launch_bounds__(256) void gemm_p(const float* __restrict__ W,
        const u64* __restrict__ sob,
        const float* __restrict__ scale, const float* __restrict__ bias,
        float* __restrict__ out) {
    __shared__ float As[GBK][ASTR];
    __shared__ float Bs[GBK][GBN];
    const int tb = blockIdx.z;
    const int m0 = blockIdx.x * GBM;
    const int wq = blockIdx.y;
    const int n0 = wq * 64;
    const int tid = threadIdx.x;
    const int wave = tid >> 6, lane = tid & 63;
    const int r0 = (tid >> 4) * 4, c0 = (tid & 15) * 4;

    float acc[4][4];
    #pragma unroll
    for (int i = 0; i < 4; ++i)
        #pragma unroll
        for (int j = 0; j < 4; ++j) acc[i][j] = 0.f;

    const u64* sp = sob + (size_t)tb * CV_DIM * NW + wq;
    for (int k0 = 0; k0 < CV_DIM; k0 += GBK) {
        #pragma unroll
        for (int rep = 0; rep < 2; ++rep) {
            int lin = rep * 256 + tid;
            int row = lin >> 3, g = (lin & 7) * 4;
            const float4 a4 = *reinterpret_cast<const float4*>(W + (size_t)(m0 + row) * CV_DIM + k0 + g);
            As[g + 0][row] = a4.x;
            As[g + 1][row] = a4.y;
            As[g + 2][row] = a4.z;
            As[g + 3][row] = a4.w;
        }
        #pragma unroll
        for (int q8 = 0; q8 < 8; ++q8) {
            int kk = wave * 8 + q8;
            u64 w = sp[(size_t)(k0 + kk) * NW];
            Bs[kk][lane] = (float)((w >> lane) & 1ULL);
        }
        __syncthreads();
        #pragma unroll
        for (int kk = 0; kk < GBK; ++kk) {
            const float4 a4 = *reinterpret_cast<const float4*>(&As[kk][r0]);
            float av[4] = {a4.x, a4.y, a4.z, a4.w};
            const float4 b4 = *reinterpret_cast<const float4*>(&Bs[kk][c0]);
            float bv[4] = {b4.x, b4.y, b4.z, b4.w};
            #pragma unroll
            for (int i = 0; i < 4; ++i)
                #pragma unroll
                for (int j = 0; j < 4; ++j)
                    acc[i][j] += av[i] * bv[j];
        }
        __syncthreads();
    }
    #pragma unroll
    for (int i = 0; i < 4; ++i) {
        float sc = scale[m0 + r0 + i], bi = bias[m0 + r0 + i];
        float4 r;
        r.x = __fadd_rn(__fmul_rn(acc[i][0], sc), bi);
        r.y = __fadd_rn(__fmul_rn(acc[i][1], sc), bi);
        r.z = __fadd_rn(__fmul_rn(acc[i][2], sc), bi);
        r.w = __fadd_rn(__fmul_rn(acc[i][3], sc), bi);
        *reinterpret_cast<float4*>(out + (size_t)tb * (C_DIM * N_DIM)
                                   + (size_t)(m0 + r0 + i) * N_DIM + n0 + c0) = r;
    }
}

extern "C" void kernel_launch(void* const* d_in, const int* in_sizes, int n_in,
                              void* d_out, int out_size, void* d_ws, size_t ws_size,
                              hipStream_t stream) {
    const float* x    = (const float*)d_in[0];
    const float* pos  = (const float*)d_in[1];
    const float* q_w  = (const float*)d_in[2];
    const float* q_s  = (const float*)d_in[3];
    const float* q_b  = (const float*)d_in[4];
    const float* k_w  = (const float*)d_in[5];
    const float* k_s  = (const float*)d_in[6];
    const float* k_b  = (const float*)d_in[7];
    const float* v_w  = (const float*)d_in[8];
    const float* v_s  = (const float*)d_in[9];
    const float* v_b  = (const float*)d_in[10];
    const float* p_w  = (const float*)d_in[11];
    const float* p_s  = (const float*)d_in[12];
    const float* p_b  = (const float*)d_in[13];
    float* out = (float*)d_out;

    char* ws = (char*)d_ws;
    u64* sxb  = (u64*)ws;                                       // [T][B*512][9]  1,179,648 B
    u64* qkvb = (u64*)(ws + 1179648);                           // [T*B][3072][9] 7,077,888 B
    float* kv = (float*)(ws + 1179648 + 7077888);               // [T*B*8][64][256] 16,777,216 B
    u64* sob  = (u64*)(ws + 1179648 + 7077888 + 16777216);      // [T*B][2048][9] 4,718,592 B
    // total: 29,753,344 B

    // 1) LIF on x+pos -> packed spikes
    lif_x_pack<<<B_DIM * C_DIM, 576, 0, stream>>>(x, pos, sxb);

    // 2) fused q/k/v GEMM + LIF + pack (loops t internally)
    dim3 gq(C_DIM / GBM, NW, B_DIM);    // (8,9,8)
    gemm_qkv_fused<<<gq, 256, 0, stream>>>(q_w, sxb, q_s, q_b, qkvb, C_DIM, C_DIM, 0);
    gemm_qkv_fused<<<gq, 256, 0, stream>>>(k_w, sxb, k_s, k_b, qkvb, C_DIM, C_DIM, 512);
    dim3 gv(CV_DIM / GBM, NW, B_DIM);   // (32,9,8)
    gemm_qkv_fused<<<gv, 256, 0, stream>>>(v_w, sxb, v_s, v_b, qkvb, CV_DIM, C_DIM, 1024);

    // 3) attention: exact popcount kv, then fused o + LIF + pack
    kv_pop_kernel<<<TB_DIM * 8, 256, 0, stream>>>(qkvb, kv);
    o_attn_fused<<<B_DIM * 8 * 16, 576, 0, stream>>>(qkvb, kv, sob);

    // 4) output projection
    dim3 gp(C_DIM / GBM, NW, TB_DIM);   // (8,9,32)
    gemm_p<<<gp, 256, 0, stream>>>(p_w, sob, p_s, p_b, out);
}

// Round 4
// 584.485 us; speedup vs baseline: 8.8535x; 2.6033x over previous
//
#include <hip/hip_runtime.h>
#include <cstdint>

#define T_DIM 4
#define B_DIM 8
#define C_DIM 512
#define N_DIM 576
#define CV_DIM 2048
#define TB_DIM 32
#define NW 9              // u64 words per row of N=576

typedef unsigned long long u64;
typedef unsigned char u8;
typedef uint32_t u32;
typedef _Float16 h16;
typedef __attribute__((ext_vector_type(8))) _Float16 f16x8;
typedef __attribute__((ext_vector_type(16))) float f32x16;

// ---------------- Stage 1: LIF over (x + pos) -> bit-packed spikes ----------------
__global__ __launch_bounds__(576) void lif_x_pack(const float* __restrict__ x,
                                                  const float* __restrict__ pos,
                                                  u64* __restrict__ sxb) {
    const int bc = blockIdx.x;             // b*512 + c
    const int c = bc & (C_DIM - 1);
    const int n = threadIdx.x;             // 0..575
    const int lane = n & 63, wv = n >> 6;
    const float p = pos[c * N_DIM + n];
    const size_t BCN = (size_t)B_DIM * C_DIM * N_DIM;
    float mem = 0.f, s = 0.f;
    for (int t = 0; t < T_DIM; ++t) {
        float xt = x[t * BCN + (size_t)bc * N_DIM + n] + p;
        mem = mem * 0.25f * (1.f - s) + xt;
        s = (mem > 0.5f) ? 1.f : 0.f;
        u64 m = __ballot(s > 0.f);
        if (lane == 0) sxb[((size_t)t * (B_DIM * C_DIM) + bc) * NW + wv] = m;
    }
}

// ---------------- Weight split: W*4096 = h1 + h2 (f16 pair, ~fp32-exact) ----------------
__global__ __launch_bounds__(256) void split_qkv(const float* __restrict__ q_w,
                                                 const float* __restrict__ k_w,
                                                 const float* __restrict__ v_w,
                                                 h16* __restrict__ wp) {   // [2][3072][512]
    int i = blockIdx.x * 256 + threadIdx.x;        // 196608 groups of 8
    int row = i >> 6;
    int g8 = (i & 63) * 8;
    const float* src = (row < 512) ? q_w + (size_t)row * 512
                     : (row < 1024) ? k_w + (size_t)(row - 512) * 512
                                    : v_w + (size_t)(row - 1024) * 512;
    float4 a = *(const float4*)(src + g8);
    float4 b = *(const float4*)(src + g8 + 4);
    float v[8] = {a.x, a.y, a.z, a.w, b.x, b.y, b.z, b.w};
    f16x8 vh, vl;
    #pragma unroll
    for (int j = 0; j < 8; ++j) {
        float w = v[j] * 4096.f;
        h16 h1 = (h16)w;
        float r = w - (float)h1;
        vh[j] = h1;
        vl[j] = (h16)r;
    }
    *(f16x8*)(wp + (size_t)row * 512 + g8) = vh;
    *(f16x8*)(wp + (size_t)3072 * 512 + (size_t)row * 512 + g8) = vl;
}

__global__ __launch_bounds__(256) void split_p(const float* __restrict__ p_w,
                                               h16* __restrict__ wp) {     // [2][512][2048]
    int i = blockIdx.x * 256 + threadIdx.x;        // 131072 groups of 8
    int row = i >> 8;
    int g8 = (i & 255) * 8;
    const float* src = p_w + (size_t)row * 2048;
    float4 a = *(const float4*)(src + g8);
    float4 b = *(const float4*)(src + g8 + 4);
    float v[8] = {a.x, a.y, a.z, a.w, b.x, b.y, b.z, b.w};
    f16x8 vh, vl;
    #pragma unroll
    for (int j = 0; j < 8; ++j) {
        float w = v[j] * 4096.f;
        h16 h1 = (h16)w;
        float r = w - (float)h1;
        vh[j] = h1;
        vl[j] = (h16)r;
    }
    *(f16x8*)(wp + (size_t)row * 2048 + g8) = vh;
    *(f16x8*)(wp + (size_t)512 * 2048 + (size_t)row * 2048 + g8) = vl;
}

__global__ __launch_bounds__(256) void concat_sb(const float* __restrict__ qs, const float* __restrict__ qb,
                                                 const float* __restrict__ ks, const float* __restrict__ kb,
                                                 const float* __restrict__ vs, const float* __restrict__ vb,
                                                 float* __restrict__ sc, float* __restrict__ bi) {
    int i = blockIdx.x * 256 + threadIdx.x;
    if (i >= 3072) return;
    if (i < 512)       { sc[i] = qs[i];        bi[i] = qb[i]; }
    else if (i < 1024) { sc[i] = ks[i - 512];  bi[i] = kb[i - 512]; }
    else               { sc[i] = vs[i - 1024]; bi[i] = vb[i - 1024]; }
}

// ---------------- MFMA GEMM qkv: [3072,512] x spikes -> LIF -> packed bits ----------------
// block: 128 rows x 64 cols(one u64 word), 4 waves (wave w: rows w*32..+32), 4 t's in flight
__global__ __launch_bounds__(256, 2) void gemm_qkv_mfma(
        const h16* __restrict__ wp,     // [2][3072][512]
        const u64* __restrict__ sxb,    // [T][B*512][9]
        const float* __restrict__ sc,   // [3072]
        const float* __restrict__ bi,
        u64* __restrict__ qkvb)         // [T*B][3072][9]
{
    __shared__ h16 Ash[2][128][40];            // 20.5 KB, 80B rows, granule-XOR swizzle
    __shared__ h16 Bsh[T_DIM][64][40];         // 20.5 KB
    __shared__ __align__(16) u64 Wrd[2][T_DIM][32];

    const int b   = blockIdx.z;
    const int m0  = blockIdx.x * 128;
    const int wq  = blockIdx.y;
    const int tid = threadIdx.x;
    const int lane = tid & 63;
    const int wv   = tid >> 6;
    const int l31  = lane & 31;
    const int lhi  = lane >> 5;

    // staging roles
    const int As_s = tid >> 7, As_m = tid & 127;
    const h16* wsrc = wp + ((size_t)As_s * 3072 + m0 + As_m) * 512;
    const int As_sw = (As_m >> 3) & 3;
    const u64* wsx = sxb + ((size_t)(tid >> 5) * (B_DIM * C_DIM) + (size_t)b * C_DIM + (tid & 31)) * NW + wq;
    const int swn = (lane >> 3) & 3;

    f32x16 acc[T_DIM][2];
    #pragma unroll
    for (int t = 0; t < T_DIM; ++t)
        #pragma unroll
        for (int nf = 0; nf < 2; ++nf)
            acc[t][nf] = (f32x16)(0.f);

    if (tid < 128) Wrd[0][tid >> 5][tid & 31] = wsx[0];
    __syncthreads();

    int buf = 0;
    for (int k0 = 0; k0 < 512; k0 += 32) {
        // ---- phase 1: stage A(k0), expand B(k0) from Wrd[buf], prefetch words(k0+32)
        {
            const uint4* s4 = (const uint4*)(wsrc + k0);
            uint4 g0 = s4[0], g1 = s4[1], g2 = s4[2], g3 = s4[3];
            *(uint4*)&Ash[As_s][As_m][8 * (0 ^ As_sw)] = g0;
            *(uint4*)&Ash[As_s][As_m][8 * (1 ^ As_sw)] = g1;
            *(uint4*)&Ash[As_s][As_m][8 * (2 ^ As_sw)] = g2;
            *(uint4*)&Ash[As_s][As_m][8 * (3 ^ As_sw)] = g3;
        }
        #pragma unroll
        for (int g = 0; g < 4; ++g) {
            u32 w4[4];
            #pragma unroll
            for (int p = 0; p < 4; ++p) {
                u32 b0 = (u32)(Wrd[buf][wv][g * 8 + 2 * p]     >> lane) & 1u;
                u32 b1 = (u32)(Wrd[buf][wv][g * 8 + 2 * p + 1] >> lane) & 1u;
                w4[p] = (b0 ? 0x3C00u : 0u) | (b1 ? 0x3C000000u : 0u);
            }
            *(uint4*)&Bsh[wv][lane][8 * (g ^ swn)] = uint4{w4[0], w4[1], w4[2], w4[3]};
        }
        if (tid < 128 && k0 + 32 < 512)
            Wrd[buf ^ 1][tid >> 5][tid & 31] = wsx[(size_t)(k0 + 32) * NW];
        __syncthreads();

        // ---- phase 2: MFMA
        const int swA = (l31 >> 3) & 3;
        #pragma unroll
        for (int sub = 0; sub < 2; ++sub) {
            const int gK = lhi + 2 * sub;
            f16x8 a0 = *(const f16x8*)&Ash[0][wv * 32 + l31][8 * (gK ^ swA)];
            f16x8 a1 = *(const f16x8*)&Ash[1][wv * 32 + l31][8 * (gK ^ swA)];
            #pragma unroll
            for (int t = 0; t < T_DIM; ++t) {
                f16x8 b0 = *(const f16x8*)&Bsh[t][l31][8 * (gK ^ swA)];
                f16x8 b1 = *(const f16x8*)&Bsh[t][32 + l31][8 * (gK ^ swA)];
                acc[t][0] = __builtin_amdgcn_mfma_f32_32x32x16_f16(a0, b0, acc[t][0], 0, 0, 0);
                acc[t][0] = __builtin_amdgcn_mfma_f32_32x32x16_f16(a1, b0, acc[t][0], 0, 0, 0);
                acc[t][1] = __builtin_amdgcn_mfma_f32_32x32x16_f16(a0, b1, acc[t][1], 0, 0, 0);
                acc[t][1] = __builtin_amdgcn_mfma_f32_32x32x16_f16(a1, b1, acc[t][1], 0, 0, 0);
            }
        }
        __syncthreads();
        buf ^= 1;
    }

    // ---- epilogue: unscale (exact 2^-12), conv_bn, LIF over t, ballot-pack
    const float inv = 0x1p-12f;
    #pragma unroll
    for (int r = 0; r < 16; ++r) {
        int row = m0 + wv * 32 + (r & 3) + 8 * (r >> 2) + 4 * lhi;
        float scv = sc[row], biv = bi[row];
        float mem0 = 0.f, spk0 = 0.f, mem1 = 0.f, spk1 = 0.f;
        #pragma unroll
        for (int t = 0; t < T_DIM; ++t) {
            float y0 = __fadd_rn(__fmul_rn(acc[t][0][r] * inv, scv), biv);
            float y1 = __fadd_rn(__fmul_rn(acc[t][1][r] * inv, scv), biv);
            mem0 = mem0 * 0.25f * (1.f - spk0) + y0; spk0 = (mem0 > 0.5f) ? 1.f : 0.f;
            mem1 = mem1 * 0.25f * (1.f - spk1) + y1; spk1 = (mem1 > 0.5f) ? 1.f : 0.f;
            u64 B0 = __ballot(spk0 > 0.f);
            u64 B1 = __ballot(spk1 > 0.f);
            u64 wrd = (lhi == 0) ? ((B0 & 0xFFFFFFFFull) | (B1 << 32))
                                 : ((B0 >> 32) | (B1 & 0xFFFFFFFF00000000ull));
            if (l31 == 0)
                qkvb[((size_t)(t * B_DIM + b) * 3072 + row) * NW + wq] = wrd;
        }
    }
}

// ---------------- MFMA GEMM p: [512,2048] x o-spikes -> scale/bias -> out ----------------
__global__ __launch_bounds__(256, 2) void gemm_p_mfma(
        const h16* __restrict__ wp,     // [2][512][2048]
        const u64* __restrict__ sob,    // [TB][2048][9]
        const float* __restrict__ ps,
        const float* __restrict__ pb,
        float* __restrict__ out)        // [TB][512][576]
{
    __shared__ h16 Ash[2][128][40];
    __shared__ h16 Bsh[64][40];
    __shared__ __align__(16) u64 Wrd[2][32];

    const int tb  = blockIdx.z;
    const int m0  = blockIdx.x * 128;
    const int wq  = blockIdx.y;
    const int tid = threadIdx.x;
    const int lane = tid & 63;
    const int wv   = tid >> 6;
    const int l31  = lane & 31;
    const int lhi  = lane >> 5;

    const int As_s = tid >> 7, As_m = tid & 127;
    const h16* wsrc = wp + ((size_t)As_s * 512 + m0 + As_m) * 2048;
    const int As_sw = (As_m >> 3) & 3;
    const u64* wsb = sob + ((size_t)tb * CV_DIM + tid) * NW + wq;   // valid for tid<32
    const int Bx_n = tid & 63, Bx_g = tid >> 6;
    const int Bx_sw = (Bx_n >> 3) & 3;

    f32x16 acc0 = (f32x16)(0.f), acc1 = (f32x16)(0.f);

    if (tid < 32) Wrd[0][tid] = wsb[0];
    __syncthreads();

    int buf = 0;
    for (int k0 = 0; k0 < CV_DIM; k0 += 32) {
        {
            const uint4* s4 = (const uint4*)(wsrc + k0);
            uint4 g0 = s4[0], g1 = s4[1], g2 = s4[2], g3 = s4[3];
            *(uint4*)&Ash[As_s][As_m][8 * (0 ^ As_sw)] = g0;
            *(uint4*)&Ash[As_s][As_m][8 * (1 ^ As_sw)] = g1;
            *(uint4*)&Ash[As_s][As_m][8 * (2 ^ As_sw)] = g2;
            *(uint4*)&Ash[As_s][As_m][8 * (3 ^ As_sw)] = g3;
        }
        {
            u32 w4[4];
            #pragma unroll
            for (int p = 0; p < 4; ++p) {
                u32 b0 = (u32)(Wrd[buf][Bx_g * 8 + 2 * p]     >> Bx_n) & 1u;
                u32 b1 = (u32)(Wrd[buf][Bx_g * 8 + 2 * p + 1] >> Bx_n) & 1u;
                w4[p] = (b0 ? 0x3C00u : 0u) | (b1 ? 0x3C000000u : 0u);
            }
            *(uint4*)&Bsh[Bx_n][8 * (Bx_g ^ Bx_sw)] = uint4{w4[0], w4[1], w4[2], w4[3]};
        }
        if (tid < 32 && k0 + 32 < CV_DIM)
            Wrd[buf ^ 1][tid] = wsb[(size_t)(k0 + 32) * NW];
        __syncthreads();

        const int swA = (l31 >> 3) & 3;
        #pragma unroll
        for (int sub = 0; sub < 2; ++sub) {
            const int gK = lhi + 2 * sub;
            f16x8 a0 = *(const f16x8*)&Ash[0][wv * 32 + l31][8 * (gK ^ swA)];
            f16x8 a1 = *(const f16x8*)&Ash[1][wv * 32 + l31][8 * (gK ^ swA)];
            f16x8 b0 = *(const f16x8*)&Bsh[l31][8 * (gK ^ swA)];
            f16x8 b1 = *(const f16x8*)&Bsh[32 + l31][8 * (gK ^ swA)];
            acc0 = __builtin_amdgcn_mfma_f32_32x32x16_f16(a0, b0, acc0, 0, 0, 0);
            acc0 = __builtin_amdgcn_mfma_f32_32x32x16_f16(a1, b0, acc0, 0, 0, 0);
            acc1 = __builtin_amdgcn_mfma_f32_32x32x16_f16(a0, b1, acc1, 0, 0, 0);
            acc1 = __builtin_amdgcn_mfma_f32_32x32x16_f16(a1, b1, acc1, 0, 0, 0);
        }
        __syncthreads();
        buf ^= 1;
    }

    const float inv = 0x1p-12f;
    #pragma unroll
    for (int r = 0; r < 16; ++r) {
        int row = m0 + wv * 32 + (r & 3) + 8 * (r >> 2) + 4 * lhi;
        float scv = ps[row], biv = pb[row];
        float y0 = __fadd_rn(__fmul_rn(acc0[r] * inv, scv), biv);
        float y1 = __fadd_rn(__fmul_rn(acc1[r] * inv, scv), biv);
        float* op = out + (size_t)tb * (C_DIM * N_DIM) + (size_t)row * N_DIM + wq * 64;
        op[l31] = y0;
        op[32 + l31] = y1;
    }
}

// ---------------- Stage 4a: kv[d,e] = popcount over n of k&v ----------------
__global__ __launch_bounds__(256) void kv_pop_kernel(const u64* __restrict__ bits,
                                                     float* __restrict__ kv) {
    int tbh = blockIdx.x;
    int tb = tbh >> 3, h = tbh & 7;
    int e = threadIdx.x;
    __shared__ u64 kb[64][NW];
    const u64* kbase = bits + ((size_t)tb * 3072 + 512 + h * 64) * NW;
    const u64* vbase = bits + ((size_t)tb * 3072 + 1024 + h * 256) * NW;
    for (int i = threadIdx.x; i < 576; i += 256) kb[i / 9][i % 9] = kbase[i];
    __syncthreads();
    u64 vr[NW];
    #pragma unroll
    for (int w = 0; w < NW; ++w) vr[w] = vbase[(size_t)e * NW + w];
    float* kvp = kv + (size_t)tbh * 16384 + e;
    #pragma unroll 4
    for (int d = 0; d < 64; ++d) {
        int scnt = 0;
        #pragma unroll
        for (int w = 0; w < NW; ++w) scnt += __popcll(kb[d][w] & vr[w]);
        kvp[(size_t)d * 256] = (float)scnt;
    }
}

// ---------------- Stage 4b+5: o = 0.25 * q@kv, fused LIF + bit-pack ----------------
#define ECH 16
__global__ __launch_bounds__(576) void o_attn_fused(const u64* __restrict__ qkvb,
                                                    const float* __restrict__ kv,
                                                    u64* __restrict__ sob) {
    const int blk = blockIdx.x;
    const int ec = blk & 15, h = (blk >> 4) & 7, b = blk >> 7;
    const int e0 = ec * ECH;
    const int n = threadIdx.x, lane = n & 63, nw = n >> 6;
    __shared__ float kvs[T_DIM][64][ECH];
    __shared__ u64 qb[T_DIM][576];

    for (int i = n; i < T_DIM * 64 * ECH; i += 576) {
        int t = i >> 10, d = (i >> 4) & 63, e = i & 15;
        kvs[t][d][e] = kv[(((size_t)(t * 8 + b) * 8 + h) * 64 + d) * 256 + e0 + e];
    }
    #pragma unroll
    for (int t = 0; t < T_DIM; ++t)
        qb[t][n] = qkvb[((size_t)(t * 8 + b) * 3072 + h * 64) * NW + n];
    __syncthreads();

    float mem[ECH], spk[ECH];
    #pragma unroll
    for (int e = 0; e < ECH; ++e) { mem[e] = 0.f; spk[e] = 0.f; }

    for (int t = 0; t < T_DIM; ++t) {
        u64 qword = 0;
        #pragma unroll
        for (int d = 0; d < 64; ++d)
            qword |= ((qb[t][d * 9 + nw] >> lane) & 1ULL) << d;

        float acc[ECH];
        #pragma unroll
        for (int e = 0; e < ECH; ++e) acc[e] = 0.f;

        #pragma unroll 8
        for (int d = 0; d < 64; ++d) {
            float f = (float)((qword >> d) & 1ULL);
            const float4 k0 = *reinterpret_cast<const float4*>(&kvs[t][d][0]);
            const float4 k1 = *reinterpret_cast<const float4*>(&kvs[t][d][4]);
            const float4 k2 = *reinterpret_cast<const float4*>(&kvs[t][d][8]);
            const float4 k3 = *reinterpret_cast<const float4*>(&kvs[t][d][12]);
            acc[0]  += f * k0.x; acc[1]  += f * k0.y; acc[2]  += f * k0.z; acc[3]  += f * k0.w;
            acc[4]  += f * k1.x; acc[5]  += f * k1.y; acc[6]  += f * k1.z; acc[7]  += f * k1.w;
            acc[8]  += f * k2.x; acc[9]  += f * k2.y; acc[10] += f * k2.z; acc[11] += f * k2.w;
            acc[12] += f * k3.x; acc[13] += f * k3.y; acc[14] += f * k3.z; acc[15] += f * k3.w;
        }

        #pragma unroll
        for (int e = 0; e < ECH; ++e) {
            mem[e] = mem[e] * 0.25f * (1.f - spk[e]) + acc[e] * 0.25f;
            float sn = (mem[e] > 0.5f) ? 1.f : 0.f;
            spk[e] = sn;
            u64 msk = __ballot(sn > 0.f);
            if (lane == 0)
                sob[((size_t)(t * 8 + b) * CV_DIM + h * 256 + e0 + e) * NW + nw] = msk;
        }
    }
}

extern "C" void kernel_launch(void* const* d_in, const int* in_sizes, int n_in,
                              void* d_out, int out_size, void* d_ws, size_t ws_size,
                              hipStream_t stream) {
    const float* x    = (const float*)d_in[0];
    const float* pos  = (const float*)d_in[1];
    const float* q_w  = (const float*)d_in[2];
    const float* q_s  = (const float*)d_in[3];
    const float* q_b  = (const float*)d_in[4];
    const float* k_w  = (const float*)d_in[5];
    const float* k_s  = (const float*)d_in[6];
    const float* k_b  = (const float*)d_in[7];
    const float* v_w  = (const float*)d_in[8];
    const float* v_s  = (const float*)d_in[9];
    const float* v_b  = (const float*)d_in[10];
    const float* p_w  = (const float*)d_in[11];
    const float* p_s  = (const float*)d_in[12];
    const float* p_b  = (const float*)d_in[13];
    float* out = (float*)d_out;

    char* ws = (char*)d_ws;
    size_t off = 0;
    u64* sxb  = (u64*)(ws + off); off += 1179648;           // [T][B*512][9]
    u64* qkvb = (u64*)(ws + off); off += 7077888;           // [T*B][3072][9]
    float* kv = (float*)(ws + off); off += 16777216;        // [T*B*8][64][256]
    u64* sob  = (u64*)(ws + off); off += 4718592;           // [T*B][2048][9]
    h16* qkvw = (h16*)(ws + off); off += (size_t)2 * 3072 * 512 * 2;   // 6.29 MB
    h16* pw2  = (h16*)(ws + off); off += (size_t)2 * 512 * 2048 * 2;   // 4.19 MB
    float* scc = (float*)(ws + off); off += 3072 * 4;
    float* bic = (float*)(ws + off); off += 3072 * 4;
    // total ~40.3 MB

    // 0) weight splits + scale/bias concat
    split_qkv<<<768, 256, 0, stream>>>(q_w, k_w, v_w, qkvw);
    split_p<<<512, 256, 0, stream>>>(p_w, pw2);
    concat_sb<<<12, 256, 0, stream>>>(q_s, q_b, k_s, k_b, v_s, v_b, scc, bic);

    // 1) LIF on x+pos -> packed spikes
    lif_x_pack<<<B_DIM * C_DIM, 576, 0, stream>>>(x, pos, sxb);

    // 2) fused q/k/v MFMA GEMM + LIF + pack
    dim3 gq(3072 / 128, NW, B_DIM);    // (24,9,8)
    gemm_qkv_mfma<<<gq, 256, 0, stream>>>(qkvw, sxb, scc, bic, qkvb);

    // 3) attention: exact popcount kv, then fused o + LIF + pack
    kv_pop_kernel<<<TB_DIM * 8, 256, 0, stream>>>(qkvb, kv);
    o_attn_fused<<<B_DIM * 8 * 16, 576, 0, stream>>>(qkvb, kv, sob);

    // 4) output projection (MFMA)
    dim3 gp(C_DIM / 128, NW, TB_DIM);  // (4,9,32)
    gemm_p_mfma<<<gp, 256, 0, stream>>>(pw2, sob, p_s, p_b, out);
}

// Round 5
// 425.858 us; speedup vs baseline: 12.1513x; 1.3725x over previous
//
#include <hip/hip_runtime.h>
#include <cstdint>

#define T_DIM 4
#define B_DIM 8
#define C_DIM 512
#define N_DIM 576
#define CV_DIM 2048
#define TB_DIM 32
#define NW 9              // u64 words per row of N=576

typedef unsigned long long u64;
typedef unsigned char u8;
typedef uint32_t u32;
typedef _Float16 h16;
typedef __attribute__((ext_vector_type(8))) _Float16 f16x8;
typedef __attribute__((ext_vector_type(16))) float f32x16;

// ---------------- Stage 1: LIF over (x + pos) -> bit-packed spikes ----------------
__global__ __launch_bounds__(576) void lif_x_pack(const float* __restrict__ x,
                                                  const float* __restrict__ pos,
                                                  u64* __restrict__ sxb) {
    const int bc = blockIdx.x;             // b*512 + c
    const int c = bc & (C_DIM - 1);
    const int n = threadIdx.x;             // 0..575
    const int lane = n & 63, wv = n >> 6;
    const float p = pos[c * N_DIM + n];
    const size_t BCN = (size_t)B_DIM * C_DIM * N_DIM;
    float mem = 0.f, s = 0.f;
    for (int t = 0; t < T_DIM; ++t) {
        float xt = x[t * BCN + (size_t)bc * N_DIM + n] + p;
        mem = mem * 0.25f * (1.f - s) + xt;
        s = (mem > 0.5f) ? 1.f : 0.f;
        u64 m = __ballot(s > 0.f);
        if (lane == 0) sxb[((size_t)t * (B_DIM * C_DIM) + bc) * NW + wv] = m;
    }
}

// ---------------- Weight split: W*4096 = h1 + h2 (f16 pair, ~fp32-exact) ----------------
__global__ __launch_bounds__(256) void split_qkv(const float* __restrict__ q_w,
                                                 const float* __restrict__ k_w,
                                                 const float* __restrict__ v_w,
                                                 h16* __restrict__ wp) {   // [2][3072][512]
    int i = blockIdx.x * 256 + threadIdx.x;        // 196608 groups of 8
    int row = i >> 6;
    int g8 = (i & 63) * 8;
    const float* src = (row < 512) ? q_w + (size_t)row * 512
                     : (row < 1024) ? k_w + (size_t)(row - 512) * 512
                                    : v_w + (size_t)(row - 1024) * 512;
    float4 a = *(const float4*)(src + g8);
    float4 b = *(const float4*)(src + g8 + 4);
    float v[8] = {a.x, a.y, a.z, a.w, b.x, b.y, b.z, b.w};
    f16x8 vh, vl;
    #pragma unroll
    for (int j = 0; j < 8; ++j) {
        float w = v[j] * 4096.f;
        h16 h1 = (h16)w;
        float r = w - (float)h1;
        vh[j] = h1;
        vl[j] = (h16)r;
    }
    *(f16x8*)(wp + (size_t)row * 512 + g8) = vh;
    *(f16x8*)(wp + (size_t)3072 * 512 + (size_t)row * 512 + g8) = vl;
}

__global__ __launch_bounds__(256) void split_p(const float* __restrict__ p_w,
                                               h16* __restrict__ wp) {     // [2][512][2048]
    int i = blockIdx.x * 256 + threadIdx.x;        // 131072 groups of 8
    int row = i >> 8;
    int g8 = (i & 255) * 8;
    const float* src = p_w + (size_t)row * 2048;
    float4 a = *(const float4*)(src + g8);
    float4 b = *(const float4*)(src + g8 + 4);
    float v[8] = {a.x, a.y, a.z, a.w, b.x, b.y, b.z, b.w};
    f16x8 vh, vl;
    #pragma unroll
    for (int j = 0; j < 8; ++j) {
        float w = v[j] * 4096.f;
        h16 h1 = (h16)w;
        float r = w - (float)h1;
        vh[j] = h1;
        vl[j] = (h16)r;
    }
    *(f16x8*)(wp + (size_t)row * 2048 + g8) = vh;
    *(f16x8*)(wp + (size_t)512 * 2048 + (size_t)row * 2048 + g8) = vl;
}

__global__ __launch_bounds__(256) void concat_sb(const float* __restrict__ qs, const float* __restrict__ qb,
                                                 const float* __restrict__ ks, const float* __restrict__ kb,
                                                 const float* __restrict__ vs, const float* __restrict__ vb,
                                                 float* __restrict__ sc, float* __restrict__ bi) {
    int i = blockIdx.x * 256 + threadIdx.x;
    if (i >= 3072) return;
    if (i < 512)       { sc[i] = qs[i];        bi[i] = qb[i]; }
    else if (i < 1024) { sc[i] = ks[i - 512];  bi[i] = kb[i - 512]; }
    else               { sc[i] = vs[i - 1024]; bi[i] = vb[i - 1024]; }
}

// ---------------- MFMA GEMM qkv: [3072,512] x spikes -> LIF -> packed bits ----------------
__global__ __launch_bounds__(256, 2) void gemm_qkv_mfma(
        const h16* __restrict__ wp,     // [2][3072][512]
        const u64* __restrict__ sxb,    // [T][B*512][9]
        const float* __restrict__ sc,   // [3072]
        const float* __restrict__ bi,
        u64* __restrict__ qkvb)         // [T*B][3072][9]
{
    __shared__ h16 Ash[2][128][40];            // 20.5 KB, 80B rows, granule-XOR swizzle
    __shared__ h16 Bsh[T_DIM][64][40];         // 20.5 KB
    __shared__ __align__(16) u64 Wrd[2][T_DIM][32];

    const int b   = blockIdx.z;
    const int m0  = blockIdx.x * 128;
    const int wq  = blockIdx.y;
    const int tid = threadIdx.x;
    const int lane = tid & 63;
    const int wv   = tid >> 6;
    const int l31  = lane & 31;
    const int lhi  = lane >> 5;

    const int As_s = tid >> 7, As_m = tid & 127;
    const h16* wsrc = wp + ((size_t)As_s * 3072 + m0 + As_m) * 512;
    const int As_sw = (As_m >> 3) & 3;
    const u64* wsx = sxb + ((size_t)(tid >> 5) * (B_DIM * C_DIM) + (size_t)b * C_DIM + (tid & 31)) * NW + wq;
    const int swn = (lane >> 3) & 3;

    f32x16 acc[T_DIM][2];
    #pragma unroll
    for (int t = 0; t < T_DIM; ++t)
        #pragma unroll
        for (int nf = 0; nf < 2; ++nf)
            acc[t][nf] = (f32x16)(0.f);

    if (tid < 128) Wrd[0][tid >> 5][tid & 31] = wsx[0];
    __syncthreads();

    int buf = 0;
    for (int k0 = 0; k0 < 512; k0 += 32) {
        {
            const uint4* s4 = (const uint4*)(wsrc + k0);
            uint4 g0 = s4[0], g1 = s4[1], g2 = s4[2], g3 = s4[3];
            *(uint4*)&Ash[As_s][As_m][8 * (0 ^ As_sw)] = g0;
            *(uint4*)&Ash[As_s][As_m][8 * (1 ^ As_sw)] = g1;
            *(uint4*)&Ash[As_s][As_m][8 * (2 ^ As_sw)] = g2;
            *(uint4*)&Ash[As_s][As_m][8 * (3 ^ As_sw)] = g3;
        }
        #pragma unroll
        for (int g = 0; g < 4; ++g) {
            u32 w4[4];
            #pragma unroll
            for (int p = 0; p < 4; ++p) {
                u32 b0 = (u32)(Wrd[buf][wv][g * 8 + 2 * p]     >> lane) & 1u;
                u32 b1 = (u32)(Wrd[buf][wv][g * 8 + 2 * p + 1] >> lane) & 1u;
                w4[p] = (b0 ? 0x3C00u : 0u) | (b1 ? 0x3C000000u : 0u);
            }
            *(uint4*)&Bsh[wv][lane][8 * (g ^ swn)] = uint4{w4[0], w4[1], w4[2], w4[3]};
        }
        if (tid < 128 && k0 + 32 < 512)
            Wrd[buf ^ 1][tid >> 5][tid & 31] = wsx[(size_t)(k0 + 32) * NW];
        __syncthreads();

        const int swA = (l31 >> 3) & 3;
        #pragma unroll
        for (int sub = 0; sub < 2; ++sub) {
            const int gK = lhi + 2 * sub;
            f16x8 a0 = *(const f16x8*)&Ash[0][wv * 32 + l31][8 * (gK ^ swA)];
            f16x8 a1 = *(const f16x8*)&Ash[1][wv * 32 + l31][8 * (gK ^ swA)];
            #pragma unroll
            for (int t = 0; t < T_DIM; ++t) {
                f16x8 b0 = *(const f16x8*)&Bsh[t][l31][8 * (gK ^ swA)];
                f16x8 b1 = *(const f16x8*)&Bsh[t][32 + l31][8 * (gK ^ swA)];
                acc[t][0] = __builtin_amdgcn_mfma_f32_32x32x16_f16(a0, b0, acc[t][0], 0, 0, 0);
                acc[t][0] = __builtin_amdgcn_mfma_f32_32x32x16_f16(a1, b0, acc[t][0], 0, 0, 0);
                acc[t][1] = __builtin_amdgcn_mfma_f32_32x32x16_f16(a0, b1, acc[t][1], 0, 0, 0);
                acc[t][1] = __builtin_amdgcn_mfma_f32_32x32x16_f16(a1, b1, acc[t][1], 0, 0, 0);
            }
        }
        __syncthreads();
        buf ^= 1;
    }

    const float inv = 0x1p-12f;
    #pragma unroll
    for (int r = 0; r < 16; ++r) {
        int row = m0 + wv * 32 + (r & 3) + 8 * (r >> 2) + 4 * lhi;
        float scv = sc[row], biv = bi[row];
        float mem0 = 0.f, spk0 = 0.f, mem1 = 0.f, spk1 = 0.f;
        #pragma unroll
        for (int t = 0; t < T_DIM; ++t) {
            float y0 = __fadd_rn(__fmul_rn(acc[t][0][r] * inv, scv), biv);
            float y1 = __fadd_rn(__fmul_rn(acc[t][1][r] * inv, scv), biv);
            mem0 = mem0 * 0.25f * (1.f - spk0) + y0; spk0 = (mem0 > 0.5f) ? 1.f : 0.f;
            mem1 = mem1 * 0.25f * (1.f - spk1) + y1; spk1 = (mem1 > 0.5f) ? 1.f : 0.f;
            u64 B0 = __ballot(spk0 > 0.f);
            u64 B1 = __ballot(spk1 > 0.f);
            u64 wrd = (lhi == 0) ? ((B0 & 0xFFFFFFFFull) | (B1 << 32))
                                 : ((B0 >> 32) | (B1 & 0xFFFFFFFF00000000ull));
            if (l31 == 0)
                qkvb[((size_t)(t * B_DIM + b) * 3072 + row) * NW + wq] = wrd;
        }
    }
}

// ---------------- MFMA GEMM p: [512,2048] x o-spikes -> scale/bias -> out ----------------
__global__ __launch_bounds__(256, 2) void gemm_p_mfma(
        const h16* __restrict__ wp,     // [2][512][2048]
        const u64* __restrict__ sob,    // [TB][2048][9]
        const float* __restrict__ ps,
        const float* __restrict__ pb,
        float* __restrict__ out)        // [TB][512][576]
{
    __shared__ h16 Ash[2][128][40];
    __shared__ h16 Bsh[64][40];
    __shared__ __align__(16) u64 Wrd[2][32];

    const int tb  = blockIdx.z;
    const int m0  = blockIdx.x * 128;
    const int wq  = blockIdx.y;
    const int tid = threadIdx.x;
    const int lane = tid & 63;
    const int wv   = tid >> 6;
    const int l31  = lane & 31;
    const int lhi  = lane >> 5;

    const int As_s = tid >> 7, As_m = tid & 127;
    const h16* wsrc = wp + ((size_t)As_s * 512 + m0 + As_m) * 2048;
    const int As_sw = (As_m >> 3) & 3;
    const u64* wsb = sob + ((size_t)tb * CV_DIM + tid) * NW + wq;   // valid for tid<32
    const int Bx_n = tid & 63, Bx_g = tid >> 6;
    const int Bx_sw = (Bx_n >> 3) & 3;

    f32x16 acc0 = (f32x16)(0.f), acc1 = (f32x16)(0.f);

    if (tid < 32) Wrd[0][tid] = wsb[0];
    __syncthreads();

    int buf = 0;
    for (int k0 = 0; k0 < CV_DIM; k0 += 32) {
        {
            const uint4* s4 = (const uint4*)(wsrc + k0);
            uint4 g0 = s4[0], g1 = s4[1], g2 = s4[2], g3 = s4[3];
            *(uint4*)&Ash[As_s][As_m][8 * (0 ^ As_sw)] = g0;
            *(uint4*)&Ash[As_s][As_m][8 * (1 ^ As_sw)] = g1;
            *(uint4*)&Ash[As_s][As_m][8 * (2 ^ As_sw)] = g2;
            *(uint4*)&Ash[As_s][As_m][8 * (3 ^ As_sw)] = g3;
        }
        {
            u32 w4[4];
            #pragma unroll
            for (int p = 0; p < 4; ++p) {
                u32 b0 = (u32)(Wrd[buf][Bx_g * 8 + 2 * p]     >> Bx_n) & 1u;
                u32 b1 = (u32)(Wrd[buf][Bx_g * 8 + 2 * p + 1] >> Bx_n) & 1u;
                w4[p] = (b0 ? 0x3C00u : 0u) | (b1 ? 0x3C000000u : 0u);
            }
            *(uint4*)&Bsh[Bx_n][8 * (Bx_g ^ Bx_sw)] = uint4{w4[0], w4[1], w4[2], w4[3]};
        }
        if (tid < 32 && k0 + 32 < CV_DIM)
            Wrd[buf ^ 1][tid] = wsb[(size_t)(k0 + 32) * NW];
        __syncthreads();

        const int swA = (l31 >> 3) & 3;
        #pragma unroll
        for (int sub = 0; sub < 2; ++sub) {
            const int gK = lhi + 2 * sub;
            f16x8 a0 = *(const f16x8*)&Ash[0][wv * 32 + l31][8 * (gK ^ swA)];
            f16x8 a1 = *(const f16x8*)&Ash[1][wv * 32 + l31][8 * (gK ^ swA)];
            f16x8 b0 = *(const f16x8*)&Bsh[l31][8 * (gK ^ swA)];
            f16x8 b1 = *(const f16x8*)&Bsh[32 + l31][8 * (gK ^ swA)];
            acc0 = __builtin_amdgcn_mfma_f32_32x32x16_f16(a0, b0, acc0, 0, 0, 0);
            acc0 = __builtin_amdgcn_mfma_f32_32x32x16_f16(a1, b0, acc0, 0, 0, 0);
            acc1 = __builtin_amdgcn_mfma_f32_32x32x16_f16(a0, b1, acc1, 0, 0, 0);
            acc1 = __builtin_amdgcn_mfma_f32_32x32x16_f16(a1, b1, acc1, 0, 0, 0);
        }
        __syncthreads();
        buf ^= 1;
    }

    const float inv = 0x1p-12f;
    #pragma unroll
    for (int r = 0; r < 16; ++r) {
        int row = m0 + wv * 32 + (r & 3) + 8 * (r >> 2) + 4 * lhi;
        float scv = ps[row], biv = pb[row];
        float y0 = __fadd_rn(__fmul_rn(acc0[r] * inv, scv), biv);
        float y1 = __fadd_rn(__fmul_rn(acc1[r] * inv, scv), biv);
        float* op = out + (size_t)tb * (C_DIM * N_DIM) + (size_t)row * N_DIM + wq * 64;
        op[l31] = y0;
        op[32 + l31] = y1;
    }
}

// ---------------- Stage 4a: kv^T[e][d] = popcount over n of k&v (f16-exact ints) ----------------
__global__ __launch_bounds__(256) void kv_pop_kernel(const u64* __restrict__ bits,
                                                     h16* __restrict__ kvt) {  // [tbh][256 e][64 d]
    int tbh = blockIdx.x;               // (t*8+b)*8+h
    int tb = tbh >> 3, h = tbh & 7;
    int e = threadIdx.x;
    __shared__ u64 kb[64][NW];
    const u64* kbase = bits + ((size_t)tb * 3072 + 512 + h * 64) * NW;
    const u64* vbase = bits + ((size_t)tb * 3072 + 1024 + h * 256) * NW;
    for (int i = threadIdx.x; i < 576; i += 256) kb[i / 9][i % 9] = kbase[i];
    __syncthreads();
    u64 vr[NW];
    #pragma unroll
    for (int w = 0; w < NW; ++w) vr[w] = vbase[(size_t)e * NW + w];
    h16* outp = kvt + (size_t)tbh * 16384 + (size_t)e * 64;
    for (int d0 = 0; d0 < 64; d0 += 4) {
        ushort4 pk;
        unsigned short* pp = (unsigned short*)&pk;
        #pragma unroll
        for (int j = 0; j < 4; ++j) {
            int scnt = 0;
            #pragma unroll
            for (int w = 0; w < NW; ++w) scnt += __popcll(kb[d0 + j][w] & vr[w]);
            union { h16 h; unsigned short u; } cv;
            cv.h = (h16)scnt;                 // ints <=576: exact in f16
            pp[j] = cv.u;
        }
        *(ushort4*)(outp + d0) = pk;
    }
}

// ---------------- Stage 4b+5: o^T = kv^T @ q^T via MFMA, fused LIF + bit-pack ----------------
// block: (nw, ec, b*8+h). 4 waves; wave w -> e-tile w (32 rows), 2 n-tiles (64 n of word nw).
__global__ __launch_bounds__(256, 2) void o_attn_mfma(const u64* __restrict__ qkvb,
                                                      const h16* __restrict__ kvt,
                                                      u64* __restrict__ sob) {
    const int nw = blockIdx.x;             // 0..8
    const int ec = blockIdx.y;             // 0..1 (e half: 128 rows)
    const int bh = blockIdx.z;             // 0..63
    const int b = bh >> 3, h = bh & 7;
    const int tid = threadIdx.x;
    const int lane = tid & 63, wv = tid >> 6, l31 = lane & 31, lhi = lane >> 5;

    __shared__ h16 kvs[128][64];           // 16 KB, granule-XOR swizzled rows
    __shared__ __align__(16) u64 qbs[64];  // q bits for this n-word, d=0..63

    const int st_row = tid >> 1;           // 0..127
    const int st_half = tid & 1;           // d 0..31 / 32..63

    float mem0[16], spk0[16], mem1[16], spk1[16];
    #pragma unroll
    for (int r = 0; r < 16; ++r) { mem0[r] = 0.f; spk0[r] = 0.f; mem1[r] = 0.f; spk1[r] = 0.f; }

    for (int t = 0; t < T_DIM; ++t) {
        const int tb = t * B_DIM + b;
        __syncthreads();
        // stage kv slice [128 e][64 d] (granule-XOR swizzle: granule g -> g ^ (row&7))
        {
            const uint4* src = (const uint4*)(kvt + ((size_t)(tb * 8 + h) * 16384)
                                + (size_t)(ec * 128 + st_row) * 64 + st_half * 32);
            uint4 g0 = src[0], g1 = src[1], g2 = src[2], g3 = src[3];
            const int sw = st_row & 7;
            *(uint4*)&kvs[st_row][8 * ((st_half * 4 + 0) ^ sw)] = g0;
            *(uint4*)&kvs[st_row][8 * ((st_half * 4 + 1) ^ sw)] = g1;
            *(uint4*)&kvs[st_row][8 * ((st_half * 4 + 2) ^ sw)] = g2;
            *(uint4*)&kvs[st_row][8 * ((st_half * 4 + 3) ^ sw)] = g3;
        }
        if (tid < 64)
            qbs[tid] = qkvb[((size_t)tb * 3072 + h * 64 + tid) * NW + nw];
        __syncthreads();

        f32x16 acc0 = (f32x16)(0.f), acc1 = (f32x16)(0.f);
        const int er = wv * 32 + l31;
        const int esw = er & 7;
        const u32* qw32 = (const u32*)qbs;
        #pragma unroll
        for (int sub = 0; sub < 4; ++sub) {
            const int g = sub * 2 + lhi;
            f16x8 af = *(const f16x8*)&kvs[er][8 * (g ^ esw)];
            union { f16x8 v; unsigned short u[8]; } b0, b1;
            #pragma unroll
            for (int j = 0; j < 8; ++j) {
                const int d = sub * 16 + lhi * 8 + j;
                u32 w0 = qw32[d * 2 + 0];
                u32 w1 = qw32[d * 2 + 1];
                b0.u[j] = ((w0 >> l31) & 1u) ? (unsigned short)0x3C00 : (unsigned short)0;
                b1.u[j] = ((w1 >> l31) & 1u) ? (unsigned short)0x3C00 : (unsigned short)0;
            }
            acc0 = __builtin_amdgcn_mfma_f32_32x32x16_f16(af, b0.v, acc0, 0, 0, 0);
            acc1 = __builtin_amdgcn_mfma_f32_32x32x16_f16(af, b1.v, acc1, 0, 0, 0);
        }

        // LIF + ballot-pack (same paired-ballot scheme as gemm_qkv epilogue)
        #pragma unroll
        for (int r = 0; r < 16; ++r) {
            mem0[r] = mem0[r] * 0.25f * (1.f - spk0[r]) + acc0[r] * 0.25f;
            spk0[r] = (mem0[r] > 0.5f) ? 1.f : 0.f;
            mem1[r] = mem1[r] * 0.25f * (1.f - spk1[r]) + acc1[r] * 0.25f;
            spk1[r] = (mem1[r] > 0.5f) ? 1.f : 0.f;
            u64 B0 = __ballot(spk0[r] > 0.f);
            u64 B1 = __ballot(spk1[r] > 0.f);
            u64 wrd = (lhi == 0) ? ((B0 & 0xFFFFFFFFull) | (B1 << 32))
                                 : ((B0 >> 32) | (B1 & 0xFFFFFFFF00000000ull));
            if (l31 == 0) {
                int e = ec * 128 + wv * 32 + (r & 3) + 8 * (r >> 2) + 4 * lhi;
                sob[((size_t)tb * CV_DIM + h * 256 + e) * NW + nw] = wrd;
            }
        }
    }
}

extern "C" void kernel_launch(void* const* d_in, const int* in_sizes, int n_in,
                              void* d_out, int out_size, void* d_ws, size_t ws_size,
                              hipStream_t stream) {
    const float* x    = (const float*)d_in[0];
    const float* pos  = (const float*)d_in[1];
    const float* q_w  = (const float*)d_in[2];
    const float* q_s  = (const float*)d_in[3];
    const float* q_b  = (const float*)d_in[4];
    const float* k_w  = (const float*)d_in[5];
    const float* k_s  = (const float*)d_in[6];
    const float* k_b  = (const float*)d_in[7];
    const float* v_w  = (const float*)d_in[8];
    const float* v_s  = (const float*)d_in[9];
    const float* v_b  = (const float*)d_in[10];
    const float* p_w  = (const float*)d_in[11];
    const float* p_s  = (const float*)d_in[12];
    const float* p_b  = (const float*)d_in[13];
    float* out = (float*)d_out;

    char* ws = (char*)d_ws;
    size_t off = 0;
    u64* sxb  = (u64*)(ws + off); off += 1179648;           // [T][B*512][9]
    u64* qkvb = (u64*)(ws + off); off += 7077888;           // [T*B][3072][9]
    h16* kvt  = (h16*)(ws + off); off += 8388608;           // [T*B*8][256 e][64 d] f16
    u64* sob  = (u64*)(ws + off); off += 4718592;           // [T*B][2048][9]
    h16* qkvw = (h16*)(ws + off); off += (size_t)2 * 3072 * 512 * 2;   // 6.29 MB
    h16* pw2  = (h16*)(ws + off); off += (size_t)2 * 512 * 2048 * 2;   // 4.19 MB
    float* scc = (float*)(ws + off); off += 3072 * 4;
    float* bic = (float*)(ws + off); off += 3072 * 4;
    // total ~31.9 MB

    // 0) weight splits + scale/bias concat
    split_qkv<<<768, 256, 0, stream>>>(q_w, k_w, v_w, qkvw);
    split_p<<<512, 256, 0, stream>>>(p_w, pw2);
    concat_sb<<<12, 256, 0, stream>>>(q_s, q_b, k_s, k_b, v_s, v_b, scc, bic);

    // 1) LIF on x+pos -> packed spikes
    lif_x_pack<<<B_DIM * C_DIM, 576, 0, stream>>>(x, pos, sxb);

    // 2) fused q/k/v MFMA GEMM + LIF + pack
    dim3 gq(3072 / 128, NW, B_DIM);    // (24,9,8)
    gemm_qkv_mfma<<<gq, 256, 0, stream>>>(qkvw, sxb, scc, bic, qkvb);

    // 3) attention: popcount kv (f16 ints), then MFMA o + LIF + pack
    kv_pop_kernel<<<TB_DIM * 8, 256, 0, stream>>>(qkvb, kvt);
    dim3 go(NW, 2, B_DIM * 8);         // (9,2,64)
    o_attn_mfma<<<go, 256, 0, stream>>>(qkvb, kvt, sob);

    // 4) output projection (MFMA)
    dim3 gp(C_DIM / 128, NW, TB_DIM);  // (4,9,32)
    gemm_p_mfma<<<gp, 256, 0, stream>>>(pw2, sob, p_s, p_b, out);
}

// Round 6
// 326.739 us; speedup vs baseline: 15.8374x; 1.3034x over previous
//
#include <hip/hip_runtime.h>
#include <cstdint>

#define T_DIM 4
#define B_DIM 8
#define C_DIM 512
#define N_DIM 576
#define CV_DIM 2048
#define TB_DIM 32
#define NW 9              // u64 words per row of N=576

typedef unsigned long long u64;
typedef unsigned char u8;
typedef uint32_t u32;
typedef _Float16 h16;
typedef __attribute__((ext_vector_type(8))) _Float16 f16x8;
typedef __attribute__((ext_vector_type(16))) float f32x16;

// async global->LDS, 16B per lane; lds ptr must be wave-uniform chunk base
__device__ __forceinline__ void gload16(const void* gp, void* lp) {
    __builtin_amdgcn_global_load_lds(
        (const __attribute__((address_space(1))) void*)gp,
        (__attribute__((address_space(3))) void*)lp, 16, 0, 0);
}

// ---------------- Stage 1: LIF over (x + pos) -> dense f16 spikes, TRANSPOSED [t][b][n][c] ----------------
// c-granules (8 h16 = 16B) XOR-swizzled by (n&7) within each 64-c chunk (matches gemm_qkv frag reads).
__global__ __launch_bounds__(256) void lif_x_T(const float* __restrict__ x,
                                               const float* __restrict__ pos,
                                               h16* __restrict__ sxT) {
    const int ct = blockIdx.x, nt = blockIdx.y, b = blockIdx.z;
    const int c0 = ct * 64, n0 = nt * 64;
    __shared__ h16 T[64][64];              // [n][c] 8 KB
    const int tid = threadIdx.x;
    const int n_l = tid & 63, cg = tid >> 6;    // read role: c = c0 + cg*16 + ii, n = n0 + n_l
    const int row = tid >> 2, q = tid & 3;      // write role

    float pv[16], mem[16], spk[16];
    #pragma unroll
    for (int ii = 0; ii < 16; ++ii) {
        pv[ii] = pos[(c0 + cg * 16 + ii) * N_DIM + n0 + n_l];
        mem[ii] = 0.f; spk[ii] = 0.f;
    }
    for (int t = 0; t < T_DIM; ++t) {
        #pragma unroll
        for (int ii = 0; ii < 16; ++ii) {
            float xt = x[((size_t)(t * B_DIM + b) * C_DIM + c0 + cg * 16 + ii) * N_DIM + n0 + n_l] + pv[ii];
            mem[ii] = mem[ii] * 0.25f * (1.f - spk[ii]) + xt;
            spk[ii] = (mem[ii] > 0.5f) ? 1.f : 0.f;
            T[n_l][cg * 16 + ii] = (h16)spk[ii];
        }
        __syncthreads();
        {
            h16* dst = sxT + ((size_t)(t * B_DIM + b) * N_DIM + n0 + row) * C_DIM + c0;
            const int f = row & 7;     // (n0+row)&7 == row&7 (n0 mult of 64)
            #pragma unroll
            for (int e = 0; e < 2; ++e) {
                int gl = q + e * 4;                       // logical granule 0..7
                uint4 v = *(const uint4*)&T[row][gl * 8];
                *(uint4*)(dst + (gl ^ f) * 8) = v;        // swizzled store
            }
        }
        __syncthreads();
    }
}

// ---------------- Weight split: W*4096 = h1 + h2, granule-swizzled layout ----------------
__global__ __launch_bounds__(256) void split_qkv(const float* __restrict__ q_w,
                                                 const float* __restrict__ k_w,
                                                 const float* __restrict__ v_w,
                                                 h16* __restrict__ wp) {   // [2][3072][512]
    int i = blockIdx.x * 256 + threadIdx.x;        // 196608 granules
    int row = i >> 6;
    int g = i & 63;                                // logical granule (8 h16)
    int g8 = g * 8;
    const float* src = (row < 512) ? q_w + (size_t)row * 512
                     : (row < 1024) ? k_w + (size_t)(row - 512) * 512
                                    : v_w + (size_t)(row - 1024) * 512;
    float4 a = *(const float4*)(src + g8);
    float4 bq = *(const float4*)(src + g8 + 4);
    float v[8] = {a.x, a.y, a.z, a.w, bq.x, bq.y, bq.z, bq.w};
    f16x8 vh, vl;
    #pragma unroll
    for (int j = 0; j < 8; ++j) {
        float w = v[j] * 4096.f;
        h16 h1 = (h16)w;
        vh[j] = h1;
        vl[j] = (h16)(w - (float)h1);
    }
    int permcol = (g & ~7) * 8 + ((g & 7) ^ (row & 7)) * 8;   // swizzle within 64-c chunk
    *(f16x8*)(wp + (size_t)row * 512 + permcol) = vh;
    *(f16x8*)(wp + (size_t)3072 * 512 + (size_t)row * 512 + permcol) = vl;
}

__global__ __launch_bounds__(256) void split_p(const float* __restrict__ p_w,
                                               h16* __restrict__ wp) {     // [2][512][2048]
    int i = blockIdx.x * 256 + threadIdx.x;        // 131072 granules
    int row = i >> 8;
    int g = i & 255;
    int g8 = g * 8;
    const float* src = p_w + (size_t)row * 2048;
    float4 a = *(const float4*)(src + g8);
    float4 bq = *(const float4*)(src + g8 + 4);
    float v[8] = {a.x, a.y, a.z, a.w, bq.x, bq.y, bq.z, bq.w};
    f16x8 vh, vl;
    #pragma unroll
    for (int j = 0; j < 8; ++j) {
        float w = v[j] * 4096.f;
        h16 h1 = (h16)w;
        vh[j] = h1;
        vl[j] = (h16)(w - (float)h1);
    }
    int permcol = (g & ~7) * 8 + ((g & 7) ^ (row & 7)) * 8;
    *(f16x8*)(wp + (size_t)row * 2048 + permcol) = vh;
    *(f16x8*)(wp + (size_t)512 * 2048 + (size_t)row * 2048 + permcol) = vl;
}

__global__ __launch_bounds__(256) void concat_sb(const float* __restrict__ qs, const float* __restrict__ qb,
                                                 const float* __restrict__ ks, const float* __restrict__ kb,
                                                 const float* __restrict__ vs, const float* __restrict__ vb,
                                                 float* __restrict__ sc, float* __restrict__ bi) {
    int i = blockIdx.x * 256 + threadIdx.x;
    if (i >= 3072) return;
    if (i < 512)       { sc[i] = qs[i];        bi[i] = qb[i]; }
    else if (i < 1024) { sc[i] = ks[i - 512];  bi[i] = kb[i - 512]; }
    else               { sc[i] = vs[i - 1024]; bi[i] = vb[i - 1024]; }
}

// ---------------- MFMA GEMM qkv: global_load_lds staging, BK=64, 32-col tiles, LIF+pack ----------------
__global__ __launch_bounds__(256, 3) void gemm_qkv_mfma(
        const h16* __restrict__ wp,     // [2][3072][512] swizzled
        const h16* __restrict__ sxT,    // [T][B][576][512] swizzled
        const float* __restrict__ sc,
        const float* __restrict__ bi,
        u32* __restrict__ qkvb32)       // [T*B][3072][18] u32 (= [..][9] u64)
{
    __shared__ h16 Ah[2][128][64];             // 32 KB
    __shared__ h16 Bh[T_DIM][32][64];          // 16 KB

    const int b   = blockIdx.z;
    const int m0  = blockIdx.x * 128;
    const int wq2 = blockIdx.y;                // 0..17: n0 = wq2*32
    const int tid = threadIdx.x;
    const int lane = tid & 63;
    const int wv   = tid >> 6;
    const int l31  = lane & 31;
    const int lhi  = lane >> 5;

    const h16* aB = wp + ((size_t)(m0 + (tid >> 3))) * 512 + (tid & 7) * 8;
    const h16* bB = sxT + ((size_t)b * N_DIM + wq2 * 32 + (tid >> 3)) * 512 + (tid & 7) * 8;
    char* ldsA = (char*)&Ah[0][0][0];
    char* ldsB = (char*)&Bh[0][0][0];
    const int woff = wv * 1024;

    f32x16 acc[T_DIM];
    #pragma unroll
    for (int t = 0; t < T_DIM; ++t) acc[t] = (f32x16)(0.f);

    for (int k0 = 0; k0 < 512; k0 += 64) {
        #pragma unroll
        for (int i = 0; i < 8; ++i)
            gload16(aB + ((size_t)(i >> 2) * 3072 + (i & 3) * 32) * 512 + k0,
                    ldsA + i * 4096 + woff);
        #pragma unroll
        for (int i = 0; i < 4; ++i)
            gload16(bB + (size_t)i * (B_DIM * N_DIM) * 512 + k0,
                    ldsB + i * 4096 + woff);
        __syncthreads();

        const int fsw = l31 & 7;
        #pragma unroll
        for (int s = 0; s < 4; ++s) {
            const int g = ((s * 2 + lhi) ^ fsw) * 8;
            f16x8 a0 = *(const f16x8*)&Ah[0][wv * 32 + l31][g];
            f16x8 a1 = *(const f16x8*)&Ah[1][wv * 32 + l31][g];
            #pragma unroll
            for (int t = 0; t < T_DIM; ++t) {
                f16x8 bt = *(const f16x8*)&Bh[t][l31][g];
                acc[t] = __builtin_amdgcn_mfma_f32_32x32x16_f16(a0, bt, acc[t], 0, 0, 0);
                acc[t] = __builtin_amdgcn_mfma_f32_32x32x16_f16(a1, bt, acc[t], 0, 0, 0);
            }
        }
        __syncthreads();
    }

    // epilogue: unscale, conv_bn, LIF over t, ballot-pack (u32 halves)
    const float inv = 0x1p-12f;
    #pragma unroll
    for (int r = 0; r < 16; ++r) {
        int row = m0 + wv * 32 + (r & 3) + 8 * (r >> 2) + 4 * lhi;
        float scv = sc[row], biv = bi[row];
        float mem = 0.f, spk = 0.f;
        #pragma unroll
        for (int t = 0; t < T_DIM; ++t) {
            float y = __fadd_rn(__fmul_rn(acc[t][r] * inv, scv), biv);
            mem = mem * 0.25f * (1.f - spk) + y;
            spk = (mem > 0.5f) ? 1.f : 0.f;
            u64 Bal = __ballot(spk > 0.f);
            u32 wrd = lhi ? (u32)(Bal >> 32) : (u32)Bal;
            if (l31 == 0)
                qkvb32[((size_t)(t * B_DIM + b) * 3072 + row) * 18 + wq2] = wrd;
        }
    }
}

// ---------------- Stage 4a: kv^T[e][d] = popcount over n of k&v (f16-exact ints) ----------------
__global__ __launch_bounds__(256) void kv_pop_kernel(const u64* __restrict__ bits,
                                                     h16* __restrict__ kvt) {  // [tbh][256 e][64 d]
    int tbh = blockIdx.x;
    int tb = tbh >> 3, h = tbh & 7;
    int e = threadIdx.x;
    __shared__ u64 kb[64][NW];
    const u64* kbase = bits + ((size_t)tb * 3072 + 512 + h * 64) * NW;
    const u64* vbase = bits + ((size_t)tb * 3072 + 1024 + h * 256) * NW;
    for (int i = threadIdx.x; i < 576; i += 256) kb[i / 9][i % 9] = kbase[i];
    __syncthreads();
    u64 vr[NW];
    #pragma unroll
    for (int w = 0; w < NW; ++w) vr[w] = vbase[(size_t)e * NW + w];
    h16* outp = kvt + (size_t)tbh * 16384 + (size_t)e * 64;
    for (int d0 = 0; d0 < 64; d0 += 4) {
        ushort4 pk;
        unsigned short* pp = (unsigned short*)&pk;
        #pragma unroll
        for (int j = 0; j < 4; ++j) {
            int scnt = 0;
            #pragma unroll
            for (int w = 0; w < NW; ++w) scnt += __popcll(kb[d0 + j][w] & vr[w]);
            union { h16 h; unsigned short u; } cv;
            cv.h = (h16)scnt;
            pp[j] = cv.u;
        }
        *(ushort4*)(outp + d0) = pk;
    }
}

// ---------------- Stage 4b+5: o^T = kv^T @ q^T via MFMA, fused LIF + bit-pack ----------------
__global__ __launch_bounds__(256, 2) void o_attn_mfma(const u64* __restrict__ qkvb,
                                                      const h16* __restrict__ kvt,
                                                      u64* __restrict__ sob) {
    const int nw = blockIdx.x;
    const int ec = blockIdx.y;
    const int bh = blockIdx.z;
    const int b = bh >> 3, h = bh & 7;
    const int tid = threadIdx.x;
    const int lane = tid & 63, wv = tid >> 6, l31 = lane & 31, lhi = lane >> 5;

    __shared__ h16 kvs[128][64];
    __shared__ __align__(16) u64 qbs[64];

    const int st_row = tid >> 1;
    const int st_half = tid & 1;

    float mem0[16], spk0[16], mem1[16], spk1[16];
    #pragma unroll
    for (int r = 0; r < 16; ++r) { mem0[r] = 0.f; spk0[r] = 0.f; mem1[r] = 0.f; spk1[r] = 0.f; }

    for (int t = 0; t < T_DIM; ++t) {
        const int tb = t * B_DIM + b;
        __syncthreads();
        {
            const uint4* src = (const uint4*)(kvt + ((size_t)(tb * 8 + h) * 16384)
                                + (size_t)(ec * 128 + st_row) * 64 + st_half * 32);
            uint4 g0 = src[0], g1 = src[1], g2 = src[2], g3 = src[3];
            const int sw = st_row & 7;
            *(uint4*)&kvs[st_row][8 * ((st_half * 4 + 0) ^ sw)] = g0;
            *(uint4*)&kvs[st_row][8 * ((st_half * 4 + 1) ^ sw)] = g1;
            *(uint4*)&kvs[st_row][8 * ((st_half * 4 + 2) ^ sw)] = g2;
            *(uint4*)&kvs[st_row][8 * ((st_half * 4 + 3) ^ sw)] = g3;
        }
        if (tid < 64)
            qbs[tid] = qkvb[((size_t)tb * 3072 + h * 64 + tid) * NW + nw];
        __syncthreads();

        f32x16 acc0 = (f32x16)(0.f), acc1 = (f32x16)(0.f);
        const int er = wv * 32 + l31;
        const int esw = er & 7;
        const u32* qw32 = (const u32*)qbs;
        #pragma unroll
        for (int sub = 0; sub < 4; ++sub) {
            const int g = sub * 2 + lhi;
            f16x8 af = *(const f16x8*)&kvs[er][8 * (g ^ esw)];
            union { f16x8 v; unsigned short u[8]; } b0, b1;
            #pragma unroll
            for (int j = 0; j < 8; ++j) {
                const int d = sub * 16 + lhi * 8 + j;
                u32 w0 = qw32[d * 2 + 0];
                u32 w1 = qw32[d * 2 + 1];
                b0.u[j] = ((w0 >> l31) & 1u) ? (unsigned short)0x3C00 : (unsigned short)0;
                b1.u[j] = ((w1 >> l31) & 1u) ? (unsigned short)0x3C00 : (unsigned short)0;
            }
            acc0 = __builtin_amdgcn_mfma_f32_32x32x16_f16(af, b0.v, acc0, 0, 0, 0);
            acc1 = __builtin_amdgcn_mfma_f32_32x32x16_f16(af, b1.v, acc1, 0, 0, 0);
        }

        #pragma unroll
        for (int r = 0; r < 16; ++r) {
            mem0[r] = mem0[r] * 0.25f * (1.f - spk0[r]) + acc0[r] * 0.25f;
            spk0[r] = (mem0[r] > 0.5f) ? 1.f : 0.f;
            mem1[r] = mem1[r] * 0.25f * (1.f - spk1[r]) + acc1[r] * 0.25f;
            spk1[r] = (mem1[r] > 0.5f) ? 1.f : 0.f;
            u64 B0 = __ballot(spk0[r] > 0.f);
            u64 B1 = __ballot(spk1[r] > 0.f);
            u64 wrd = (lhi == 0) ? ((B0 & 0xFFFFFFFFull) | (B1 << 32))
                                 : ((B0 >> 32) | (B1 & 0xFFFFFFFF00000000ull));
            if (l31 == 0) {
                int e = ec * 128 + wv * 32 + (r & 3) + 8 * (r >> 2) + 4 * lhi;
                sob[((size_t)tb * CV_DIM + h * 256 + e) * NW + nw] = wrd;
            }
        }
    }
}

// ---------------- MFMA GEMM p: gload_lds A, BK=64, swizzled bit-expand B ----------------
__global__ __launch_bounds__(256, 3) void gemm_p_mfma(
        const h16* __restrict__ wp,     // [2][512][2048] swizzled
        const u64* __restrict__ sob,    // [TB][2048][9]
        const float* __restrict__ ps,
        const float* __restrict__ pb,
        float* __restrict__ out)        // [TB][512][576]
{
    __shared__ h16 Ah[2][128][64];             // 32 KB
    __shared__ h16 Bsh[64][64];                // 8 KB
    __shared__ __align__(16) u64 Wrd[2][64];

    const int tb  = blockIdx.z;
    const int m0  = blockIdx.x * 128;
    const int wq  = blockIdx.y;
    const int tid = threadIdx.x;
    const int lane = tid & 63;
    const int wv   = tid >> 6;
    const int l31  = lane & 31;
    const int lhi  = lane >> 5;

    const h16* aB = wp + ((size_t)(m0 + (tid >> 3))) * 2048 + (tid & 7) * 8;
    char* ldsA = (char*)&Ah[0][0][0];
    const int woff = wv * 1024;
    const u64* wsb = sob + (size_t)tb * CV_DIM * NW + wq;
    const int Bx_n = tid & 63, Bx_g = tid >> 6;

    f32x16 acc0 = (f32x16)(0.f), acc1 = (f32x16)(0.f);

    if (tid < 64) Wrd[0][tid] = wsb[(size_t)tid * NW];
    __syncthreads();

    int buf = 0;
    for (int k0 = 0; k0 < CV_DIM; k0 += 64) {
        #pragma unroll
        for (int i = 0; i < 8; ++i)
            gload16(aB + ((size_t)(i >> 2) * 512 + (i & 3) * 32) * 2048 + k0,
                    ldsA + i * 4096 + woff);
        #pragma unroll
        for (int e = 0; e < 2; ++e) {
            int gg = Bx_g + e * 4;
            u32 w4[4];
            #pragma unroll
            for (int p = 0; p < 4; ++p) {
                u32 b0 = (u32)(Wrd[buf][gg * 8 + 2 * p]     >> Bx_n) & 1u;
                u32 b1 = (u32)(Wrd[buf][gg * 8 + 2 * p + 1] >> Bx_n) & 1u;
                w4[p] = (b0 ? 0x3C00u : 0u) | (b1 ? 0x3C000000u : 0u);
            }
            *(uint4*)&Bsh[Bx_n][8 * (gg ^ (Bx_n & 7))] = uint4{w4[0], w4[1], w4[2], w4[3]};
        }
        if (tid < 64 && k0 + 64 < CV_DIM)
            Wrd[buf ^ 1][tid] = wsb[(size_t)(k0 + 64 + tid) * NW];
        __syncthreads();

        const int fsw = l31 & 7;
        #pragma unroll
        for (int s = 0; s < 4; ++s) {
            const int g = ((s * 2 + lhi) ^ fsw) * 8;
            f16x8 a0 = *(const f16x8*)&Ah[0][wv * 32 + l31][g];
            f16x8 a1 = *(const f16x8*)&Ah[1][wv * 32 + l31][g];
            f16x8 b0 = *(const f16x8*)&Bsh[l31][g];
            f16x8 b1 = *(const f16x8*)&Bsh[32 + l31][g];
            acc0 = __builtin_amdgcn_mfma_f32_32x32x16_f16(a0, b0, acc0, 0, 0, 0);
            acc0 = __builtin_amdgcn_mfma_f32_32x32x16_f16(a1, b0, acc0, 0, 0, 0);
            acc1 = __builtin_amdgcn_mfma_f32_32x32x16_f16(a0, b1, acc1, 0, 0, 0);
            acc1 = __builtin_amdgcn_mfma_f32_32x32x16_f16(a1, b1, acc1, 0, 0, 0);
        }
        __syncthreads();
        buf ^= 1;
    }

    const float inv = 0x1p-12f;
    #pragma unroll
    for (int r = 0; r < 16; ++r) {
        int row = m0 + wv * 32 + (r & 3) + 8 * (r >> 2) + 4 * lhi;
        float scv = ps[row], biv = pb[row];
        float y0 = __fadd_rn(__fmul_rn(acc0[r] * inv, scv), biv);
        float y1 = __fadd_rn(__fmul_rn(acc1[r] * inv, scv), biv);
        float* op = out + (size_t)tb * (C_DIM * N_DIM) + (size_t)row * N_DIM + wq * 64;
        op[l31] = y0;
        op[32 + l31] = y1;
    }
}

extern "C" void kernel_launch(void* const* d_in, const int* in_sizes, int n_in,
                              void* d_out, int out_size, void* d_ws, size_t ws_size,
                              hipStream_t stream) {
    const float* x    = (const float*)d_in[0];
    const float* pos  = (const float*)d_in[1];
    const float* q_w  = (const float*)d_in[2];
    const float* q_s  = (const float*)d_in[3];
    const float* q_b  = (const float*)d_in[4];
    const float* k_w  = (const float*)d_in[5];
    const float* k_s  = (const float*)d_in[6];
    const float* k_b  = (const float*)d_in[7];
    const float* v_w  = (const float*)d_in[8];
    const float* v_s  = (const float*)d_in[9];
    const float* v_b  = (const float*)d_in[10];
    const float* p_w  = (const float*)d_in[11];
    const float* p_s  = (const float*)d_in[12];
    const float* p_b  = (const float*)d_in[13];
    float* out = (float*)d_out;

    char* ws = (char*)d_ws;
    size_t off = 0;
    h16* sxT  = (h16*)(ws + off); off += (size_t)T_DIM * B_DIM * N_DIM * C_DIM * 2;  // 18.87 MB
    u64* qkvb = (u64*)(ws + off); off += 7077888;                                    // [T*B][3072][9]
    h16* kvt  = (h16*)(ws + off); off += 8388608;                                    // [T*B*8][256][64]
    u64* sob  = (u64*)(ws + off); off += 4718592;                                    // [T*B][2048][9]
    h16* qkvw = (h16*)(ws + off); off += (size_t)2 * 3072 * 512 * 2;                 // 6.29 MB
    h16* pw2  = (h16*)(ws + off); off += (size_t)2 * 512 * 2048 * 2;                 // 4.19 MB
    float* scc = (float*)(ws + off); off += 3072 * 4;
    float* bic = (float*)(ws + off); off += 3072 * 4;
    // total ~49.6 MB

    // 0) weight splits (swizzled) + scale/bias concat
    split_qkv<<<768, 256, 0, stream>>>(q_w, k_w, v_w, qkvw);
    split_p<<<512, 256, 0, stream>>>(p_w, pw2);
    concat_sb<<<12, 256, 0, stream>>>(q_s, q_b, k_s, k_b, v_s, v_b, scc, bic);

    // 1) LIF on x+pos -> transposed swizzled f16 spikes
    dim3 gl(C_DIM / 64, N_DIM / 64, B_DIM);   // (8,9,8)
    lif_x_T<<<gl, 256, 0, stream>>>(x, pos, sxT);

    // 2) fused q/k/v MFMA GEMM + LIF + pack
    dim3 gq(3072 / 128, 18, B_DIM);    // (24,18,8)
    gemm_qkv_mfma<<<gq, 256, 0, stream>>>(qkvw, sxT, scc, bic, (u32*)qkvb);

    // 3) attention: popcount kv (f16 ints), then MFMA o + LIF + pack
    kv_pop_kernel<<<TB_DIM * 8, 256, 0, stream>>>(qkvb, kvt);
    dim3 go(NW, 2, B_DIM * 8);         // (9,2,64)
    o_attn_mfma<<<go, 256, 0, stream>>>(qkvb, kvt, sob);

    // 4) output projection (MFMA)
    dim3 gp(C_DIM / 128, NW, TB_DIM);  // (4,9,32)
    gemm_p_mfma<<<gp, 256, 0, stream>>>(pw2, sob, p_s, p_b, out);
}

// Round 7
// 276.504 us; speedup vs baseline: 18.7148x; 1.1817x over previous
//
#include <hip/hip_runtime.h>
#include <cstdint>

#define T_DIM 4
#define B_DIM 8
#define C_DIM 512
#define N_DIM 576
#define CV_DIM 2048
#define TB_DIM 32
#define NW 9              // u64 words per row of N=576

typedef unsigned long long u64;
typedef unsigned char u8;
typedef uint32_t u32;
typedef _Float16 h16;
typedef __attribute__((ext_vector_type(8))) _Float16 f16x8;
typedef __attribute__((ext_vector_type(16))) float f32x16;

// async global->LDS, 16B per lane; lds ptr must be wave-uniform chunk base
__device__ __forceinline__ void gload16(const void* gp, void* lp) {
    __builtin_amdgcn_global_load_lds(
        (const __attribute__((address_space(1))) void*)gp,
        (__attribute__((address_space(3))) void*)lp, 16, 0, 0);
}

// ---------------- Stage 1: LIF over (x + pos) -> dense f16 spikes, TRANSPOSED [t][b][n][c] ----------------
// c-granules (8 h16 = 16B) XOR-swizzled by (n&7) within each 64-c chunk (matches gemm frag reads).
__global__ __launch_bounds__(256) void lif_x_T(const float* __restrict__ x,
                                               const float* __restrict__ pos,
                                               h16* __restrict__ sxT) {
    const int ct = blockIdx.x, nt = blockIdx.y, b = blockIdx.z;
    const int c0 = ct * 64, n0 = nt * 64;
    __shared__ h16 T[64][64];              // [n][c] 8 KB
    const int tid = threadIdx.x;
    const int n_l = tid & 63, cg = tid >> 6;
    const int row = tid >> 2, q = tid & 3;

    float pv[16], mem[16], spk[16];
    #pragma unroll
    for (int ii = 0; ii < 16; ++ii) {
        pv[ii] = pos[(c0 + cg * 16 + ii) * N_DIM + n0 + n_l];
        mem[ii] = 0.f; spk[ii] = 0.f;
    }
    for (int t = 0; t < T_DIM; ++t) {
        #pragma unroll
        for (int ii = 0; ii < 16; ++ii) {
            float xt = x[((size_t)(t * B_DIM + b) * C_DIM + c0 + cg * 16 + ii) * N_DIM + n0 + n_l] + pv[ii];
            mem[ii] = mem[ii] * 0.25f * (1.f - spk[ii]) + xt;
            spk[ii] = (mem[ii] > 0.5f) ? 1.f : 0.f;
            T[n_l][cg * 16 + ii] = (h16)spk[ii];
        }
        __syncthreads();
        {
            h16* dst = sxT + ((size_t)(t * B_DIM + b) * N_DIM + n0 + row) * C_DIM + c0;
            const int f = row & 7;
            #pragma unroll
            for (int e = 0; e < 2; ++e) {
                int gl = q + e * 4;
                uint4 v = *(const uint4*)&T[row][gl * 8];
                *(uint4*)(dst + (gl ^ f) * 8) = v;
            }
        }
        __syncthreads();
    }
}

// ---------------- Weight split: W*4096 = h1 + h2, granule-swizzled layout ----------------
__global__ __launch_bounds__(256) void split_qkv(const float* __restrict__ q_w,
                                                 const float* __restrict__ k_w,
                                                 const float* __restrict__ v_w,
                                                 h16* __restrict__ wp) {   // [2][3072][512]
    int i = blockIdx.x * 256 + threadIdx.x;
    int row = i >> 6;
    int g = i & 63;
    int g8 = g * 8;
    const float* src = (row < 512) ? q_w + (size_t)row * 512
                     : (row < 1024) ? k_w + (size_t)(row - 512) * 512
                                    : v_w + (size_t)(row - 1024) * 512;
    float4 a = *(const float4*)(src + g8);
    float4 bq = *(const float4*)(src + g8 + 4);
    float v[8] = {a.x, a.y, a.z, a.w, bq.x, bq.y, bq.z, bq.w};
    f16x8 vh, vl;
    #pragma unroll
    for (int j = 0; j < 8; ++j) {
        float w = v[j] * 4096.f;
        h16 h1 = (h16)w;
        vh[j] = h1;
        vl[j] = (h16)(w - (float)h1);
    }
    int permcol = (g & ~7) * 8 + ((g & 7) ^ (row & 7)) * 8;
    *(f16x8*)(wp + (size_t)row * 512 + permcol) = vh;
    *(f16x8*)(wp + (size_t)3072 * 512 + (size_t)row * 512 + permcol) = vl;
}

__global__ __launch_bounds__(256) void split_p(const float* __restrict__ p_w,
                                               h16* __restrict__ wp) {     // [2][512][2048]
    int i = blockIdx.x * 256 + threadIdx.x;
    int row = i >> 8;
    int g = i & 255;
    int g8 = g * 8;
    const float* src = p_w + (size_t)row * 2048;
    float4 a = *(const float4*)(src + g8);
    float4 bq = *(const float4*)(src + g8 + 4);
    float v[8] = {a.x, a.y, a.z, a.w, bq.x, bq.y, bq.z, bq.w};
    f16x8 vh, vl;
    #pragma unroll
    for (int j = 0; j < 8; ++j) {
        float w = v[j] * 4096.f;
        h16 h1 = (h16)w;
        vh[j] = h1;
        vl[j] = (h16)(w - (float)h1);
    }
    int permcol = (g & ~7) * 8 + ((g & 7) ^ (row & 7)) * 8;
    *(f16x8*)(wp + (size_t)row * 2048 + permcol) = vh;
    *(f16x8*)(wp + (size_t)512 * 2048 + (size_t)row * 2048 + permcol) = vl;
}

__global__ __launch_bounds__(256) void concat_sb(const float* __restrict__ qs, const float* __restrict__ qb,
                                                 const float* __restrict__ ks, const float* __restrict__ kb,
                                                 const float* __restrict__ vs, const float* __restrict__ vb,
                                                 float* __restrict__ sc, float* __restrict__ bi) {
    int i = blockIdx.x * 256 + threadIdx.x;
    if (i >= 3072) return;
    if (i < 512)       { sc[i] = qs[i];        bi[i] = qb[i]; }
    else if (i < 1024) { sc[i] = ks[i - 512];  bi[i] = kb[i - 512]; }
    else               { sc[i] = vs[i - 1024]; bi[i] = vb[i - 1024]; }
}

// ---------------- MFMA GEMM qkv: global_load_lds staging, BK=64, 32-col tiles, LIF+pack ----------------
__global__ __launch_bounds__(256, 3) void gemm_qkv_mfma(
        const h16* __restrict__ wp,     // [2][3072][512] swizzled
        const h16* __restrict__ sxT,    // [T][B][576][512] swizzled
        const float* __restrict__ sc,
        const float* __restrict__ bi,
        u32* __restrict__ qkvb32)       // [T*B][3072][18] u32 (= [..][9] u64)
{
    __shared__ h16 Ah[2][128][64];             // 32 KB
    __shared__ h16 Bh[T_DIM][32][64];          // 16 KB

    const int b   = blockIdx.z;
    const int m0  = blockIdx.x * 128;
    const int wq2 = blockIdx.y;                // 0..17: n0 = wq2*32
    const int tid = threadIdx.x;
    const int lane = tid & 63;
    const int wv   = tid >> 6;
    const int l31  = lane & 31;
    const int lhi  = lane >> 5;

    const h16* aB = wp + ((size_t)(m0 + (tid >> 3))) * 512 + (tid & 7) * 8;
    const h16* bB = sxT + ((size_t)b * N_DIM + wq2 * 32 + (tid >> 3)) * 512 + (tid & 7) * 8;
    char* ldsA = (char*)&Ah[0][0][0];
    char* ldsB = (char*)&Bh[0][0][0];
    const int woff = wv * 1024;

    f32x16 acc[T_DIM];
    #pragma unroll
    for (int t = 0; t < T_DIM; ++t) acc[t] = (f32x16)(0.f);

    for (int k0 = 0; k0 < 512; k0 += 64) {
        #pragma unroll
        for (int i = 0; i < 8; ++i)
            gload16(aB + ((size_t)(i >> 2) * 3072 + (i & 3) * 32) * 512 + k0,
                    ldsA + i * 4096 + woff);
        #pragma unroll
        for (int i = 0; i < 4; ++i)
            gload16(bB + (size_t)i * (B_DIM * N_DIM) * 512 + k0,
                    ldsB + i * 4096 + woff);
        __syncthreads();

        const int fsw = l31 & 7;
        #pragma unroll
        for (int s = 0; s < 4; ++s) {
            const int g = ((s * 2 + lhi) ^ fsw) * 8;
            f16x8 a0 = *(const f16x8*)&Ah[0][wv * 32 + l31][g];
            f16x8 a1 = *(const f16x8*)&Ah[1][wv * 32 + l31][g];
            #pragma unroll
            for (int t = 0; t < T_DIM; ++t) {
                f16x8 bt = *(const f16x8*)&Bh[t][l31][g];
                acc[t] = __builtin_amdgcn_mfma_f32_32x32x16_f16(a0, bt, acc[t], 0, 0, 0);
                acc[t] = __builtin_amdgcn_mfma_f32_32x32x16_f16(a1, bt, acc[t], 0, 0, 0);
            }
        }
        __syncthreads();
    }

    const float inv = 0x1p-12f;
    #pragma unroll
    for (int r = 0; r < 16; ++r) {
        int row = m0 + wv * 32 + (r & 3) + 8 * (r >> 2) + 4 * lhi;
        float scv = sc[row], biv = bi[row];
        float mem = 0.f, spk = 0.f;
        #pragma unroll
        for (int t = 0; t < T_DIM; ++t) {
            float y = __fadd_rn(__fmul_rn(acc[t][r] * inv, scv), biv);
            mem = mem * 0.25f * (1.f - spk) + y;
            spk = (mem > 0.5f) ? 1.f : 0.f;
            u64 Bal = __ballot(spk > 0.f);
            u32 wrd = lhi ? (u32)(Bal >> 32) : (u32)Bal;
            if (l31 == 0)
                qkvb32[((size_t)(t * B_DIM + b) * 3072 + row) * 18 + wq2] = wrd;
        }
    }
}

// ---------------- Stage 4a: kv^T[e][d] = popcount over n of k&v (f16-exact ints) ----------------
__global__ __launch_bounds__(256) void kv_pop_kernel(const u64* __restrict__ bits,
                                                     h16* __restrict__ kvt) {  // [tbh][256 e][64 d]
    int tbh = blockIdx.x;
    int tb = tbh >> 3, h = tbh & 7;
    int e = threadIdx.x;
    __shared__ u64 kb[64][NW];
    const u64* kbase = bits + ((size_t)tb * 3072 + 512 + h * 64) * NW;
    const u64* vbase = bits + ((size_t)tb * 3072 + 1024 + h * 256) * NW;
    for (int i = threadIdx.x; i < 576; i += 256) kb[i / 9][i % 9] = kbase[i];
    __syncthreads();
    u64 vr[NW];
    #pragma unroll
    for (int w = 0; w < NW; ++w) vr[w] = vbase[(size_t)e * NW + w];
    h16* outp = kvt + (size_t)tbh * 16384 + (size_t)e * 64;
    for (int d0 = 0; d0 < 64; d0 += 4) {
        ushort4 pk;
        unsigned short* pp = (unsigned short*)&pk;
        #pragma unroll
        for (int j = 0; j < 4; ++j) {
            int scnt = 0;
            #pragma unroll
            for (int w = 0; w < NW; ++w) scnt += __popcll(kb[d0 + j][w] & vr[w]);
            union { h16 h; unsigned short u; } cv;
            cv.h = (h16)scnt;
            pp[j] = cv.u;
        }
        *(ushort4*)(outp + d0) = pk;
    }
}

// ---------------- Stage 4b+5: o^T = kv^T @ q^T via MFMA, LIF, dense transposed f16 spikes ----------------
// writes soT[tb][n][e=2048], granule-swizzled by (n&7) within 64-e chunks (gemm_p B layout)
__global__ __launch_bounds__(256, 2) void o_attn_mfma(const u64* __restrict__ qkvb,
                                                      const h16* __restrict__ kvt,
                                                      h16* __restrict__ soT) {
    const int nw = blockIdx.x;             // n-word: n0 = nw*64
    const int ec = blockIdx.y;             // e half (128)
    const int bh = blockIdx.z;
    const int b = bh >> 3, h = bh & 7;
    const int tid = threadIdx.x;
    const int lane = tid & 63, wv = tid >> 6, l31 = lane & 31, lhi = lane >> 5;

    __shared__ h16 kvs[128][64];           // 16 KB
    __shared__ __align__(16) u64 qbs[64];
    __shared__ h16 Tr[64][136];            // 17 KB transpose buffer [n][e_local], padded

    const int st_row = tid >> 1;
    const int st_half = tid & 1;

    float mem0[16], spk0[16], mem1[16], spk1[16];
    #pragma unroll
    for (int r = 0; r < 16; ++r) { mem0[r] = 0.f; spk0[r] = 0.f; mem1[r] = 0.f; spk1[r] = 0.f; }

    for (int t = 0; t < T_DIM; ++t) {
        const int tb = t * B_DIM + b;
        __syncthreads();
        {
            const uint4* src = (const uint4*)(kvt + ((size_t)(tb * 8 + h) * 16384)
                                + (size_t)(ec * 128 + st_row) * 64 + st_half * 32);
            uint4 g0 = src[0], g1 = src[1], g2 = src[2], g3 = src[3];
            const int sw = st_row & 7;
            *(uint4*)&kvs[st_row][8 * ((st_half * 4 + 0) ^ sw)] = g0;
            *(uint4*)&kvs[st_row][8 * ((st_half * 4 + 1) ^ sw)] = g1;
            *(uint4*)&kvs[st_row][8 * ((st_half * 4 + 2) ^ sw)] = g2;
            *(uint4*)&kvs[st_row][8 * ((st_half * 4 + 3) ^ sw)] = g3;
        }
        if (tid < 64)
            qbs[tid] = qkvb[((size_t)tb * 3072 + h * 64 + tid) * NW + nw];
        __syncthreads();

        f32x16 acc0 = (f32x16)(0.f), acc1 = (f32x16)(0.f);
        const int er = wv * 32 + l31;
        const int esw = er & 7;
        const u32* qw32 = (const u32*)qbs;
        #pragma unroll
        for (int sub = 0; sub < 4; ++sub) {
            const int g = sub * 2 + lhi;
            f16x8 af = *(const f16x8*)&kvs[er][8 * (g ^ esw)];
            union { f16x8 v; unsigned short u[8]; } b0, b1;
            #pragma unroll
            for (int j = 0; j < 8; ++j) {
                const int d = sub * 16 + lhi * 8 + j;
                u32 w0 = qw32[d * 2 + 0];
                u32 w1 = qw32[d * 2 + 1];
                b0.u[j] = ((w0 >> l31) & 1u) ? (unsigned short)0x3C00 : (unsigned short)0;
                b1.u[j] = ((w1 >> l31) & 1u) ? (unsigned short)0x3C00 : (unsigned short)0;
            }
            acc0 = __builtin_amdgcn_mfma_f32_32x32x16_f16(af, b0.v, acc0, 0, 0, 0);
            acc1 = __builtin_amdgcn_mfma_f32_32x32x16_f16(af, b1.v, acc1, 0, 0, 0);
        }

        // LIF (no ballots needed: dense output)
        #pragma unroll
        for (int r = 0; r < 16; ++r) {
            mem0[r] = mem0[r] * 0.25f * (1.f - spk0[r]) + acc0[r] * 0.25f;
            spk0[r] = (mem0[r] > 0.5f) ? 1.f : 0.f;
            mem1[r] = mem1[r] * 0.25f * (1.f - spk1[r]) + acc1[r] * 0.25f;
            spk1[r] = (mem1[r] > 0.5f) ? 1.f : 0.f;
        }
        // pack to Tr: acc0 col -> n = l31, acc1 -> n = 32+l31; e_local = wv*32 + 4*lhi + (r&3) + 8*(r>>2)
        #pragma unroll
        for (int q = 0; q < 4; ++q) {
            ushort4 w0, w1;
            unsigned short* p0 = (unsigned short*)&w0;
            unsigned short* p1 = (unsigned short*)&w1;
            #pragma unroll
            for (int j = 0; j < 4; ++j) {
                union { h16 hh; unsigned short uu; } c0, c1;
                c0.hh = (h16)spk0[q * 4 + j];
                c1.hh = (h16)spk1[q * 4 + j];
                p0[j] = c0.uu;
                p1[j] = c1.uu;
            }
            int e = wv * 32 + 4 * lhi + 8 * q;
            *(ushort4*)&Tr[l31][e] = w0;
            *(ushort4*)&Tr[32 + l31][e] = w1;
        }
        __syncthreads();
        // cooperative swizzled store: 1024 chunks of 16B (8 e)
        const size_t obase = ((size_t)tb * N_DIM + nw * 64) * CV_DIM + h * 256 + ec * 128;
        #pragma unroll
        for (int it = 0; it < 4; ++it) {
            int ch = it * 256 + tid;
            int n = ch >> 4, ge = ch & 15;
            uint4 v = *(const uint4*)&Tr[n][ge * 8];
            int gsw = (ge & 8) | ((ge & 7) ^ (n & 7));
            *(uint4*)(soT + obase + (size_t)n * CV_DIM + gsw * 8) = v;
        }
    }
}

// ---------------- MFMA GEMM p: pure gload_lds staging, BK=64, 4 tb per block ----------------
__global__ __launch_bounds__(256, 3) void gemm_p_mfma(
        const h16* __restrict__ wp,     // [2][512][2048] swizzled
        const h16* __restrict__ soT,    // [TB][576][2048] swizzled
        const float* __restrict__ ps,
        const float* __restrict__ pb,
        float* __restrict__ out)        // [TB][512][576]
{
    __shared__ h16 Ah[2][128][64];             // 32 KB
    __shared__ h16 Bh[4][32][64];              // 16 KB

    const int tbq = blockIdx.z;                // 0..7 : tb = tbq*4 + tt
    const int m0  = blockIdx.x * 128;
    const int wq2 = blockIdx.y;                // 0..17: n0 = wq2*32
    const int tid = threadIdx.x;
    const int lane = tid & 63;
    const int wv   = tid >> 6;
    const int l31  = lane & 31;
    const int lhi  = lane >> 5;

    const h16* aB = wp + ((size_t)(m0 + (tid >> 3))) * 2048 + (tid & 7) * 8;
    const h16* bB = soT + ((size_t)(tbq * 4) * N_DIM + wq2 * 32 + (tid >> 3)) * 2048 + (tid & 7) * 8;
    char* ldsA = (char*)&Ah[0][0][0];
    char* ldsB = (char*)&Bh[0][0][0];
    const int woff = wv * 1024;

    f32x16 acc[4];
    #pragma unroll
    for (int tt = 0; tt < 4; ++tt) acc[tt] = (f32x16)(0.f);

    for (int k0 = 0; k0 < CV_DIM; k0 += 64) {
        #pragma unroll
        for (int i = 0; i < 8; ++i)
            gload16(aB + ((size_t)(i >> 2) * 512 + (i & 3) * 32) * 2048 + k0,
                    ldsA + i * 4096 + woff);
        #pragma unroll
        for (int tt = 0; tt < 4; ++tt)
            gload16(bB + (size_t)tt * (N_DIM * CV_DIM) + k0,
                    ldsB + tt * 4096 + woff);
        __syncthreads();

        const int fsw = l31 & 7;
        #pragma unroll
        for (int s = 0; s < 4; ++s) {
            const int g = ((s * 2 + lhi) ^ fsw) * 8;
            f16x8 a0 = *(const f16x8*)&Ah[0][wv * 32 + l31][g];
            f16x8 a1 = *(const f16x8*)&Ah[1][wv * 32 + l31][g];
            #pragma unroll
            for (int tt = 0; tt < 4; ++tt) {
                f16x8 bt = *(const f16x8*)&Bh[tt][l31][g];
                acc[tt] = __builtin_amdgcn_mfma_f32_32x32x16_f16(a0, bt, acc[tt], 0, 0, 0);
                acc[tt] = __builtin_amdgcn_mfma_f32_32x32x16_f16(a1, bt, acc[tt], 0, 0, 0);
            }
        }
        __syncthreads();
    }

    const float inv = 0x1p-12f;
    #pragma unroll
    for (int r = 0; r < 16; ++r) {
        int row = m0 + wv * 32 + (r & 3) + 8 * (r >> 2) + 4 * lhi;
        float scv = ps[row], biv = pb[row];
        #pragma unroll
        for (int tt = 0; tt < 4; ++tt) {
            float y = __fadd_rn(__fmul_rn(acc[tt][r] * inv, scv), biv);
            out[(size_t)(tbq * 4 + tt) * (C_DIM * N_DIM) + (size_t)row * N_DIM + wq2 * 32 + l31] = y;
        }
    }
}

extern "C" void kernel_launch(void* const* d_in, const int* in_sizes, int n_in,
                              void* d_out, int out_size, void* d_ws, size_t ws_size,
                              hipStream_t stream) {
    const float* x    = (const float*)d_in[0];
    const float* pos  = (const float*)d_in[1];
    const float* q_w  = (const float*)d_in[2];
    const float* q_s  = (const float*)d_in[3];
    const float* q_b  = (const float*)d_in[4];
    const float* k_w  = (const float*)d_in[5];
    const float* k_s  = (const float*)d_in[6];
    const float* k_b  = (const float*)d_in[7];
    const float* v_w  = (const float*)d_in[8];
    const float* v_s  = (const float*)d_in[9];
    const float* v_b  = (const float*)d_in[10];
    const float* p_w  = (const float*)d_in[11];
    const float* p_s  = (const float*)d_in[12];
    const float* p_b  = (const float*)d_in[13];
    float* out = (float*)d_out;

    char* ws = (char*)d_ws;
    size_t off = 0;
    u64* qkvb = (u64*)(ws + off); off += 7077888;            // [T*B][3072][9]
    h16* kvt  = (h16*)(ws + off); off += 8388608;            // [T*B*8][256][64]
    h16* pw2  = (h16*)(ws + off); off += (size_t)2 * 512 * 2048 * 2;   // 4.19 MB
    float* scc = (float*)(ws + off); off += 3072 * 4;
    float* bic = (float*)(ws + off); off += 3072 * 4;
    // aliased region: {sxT (18.9MB) + qkvw (6.3MB)} dead after gemm_qkv; soT (75.5MB) overlays it
    char* region = ws + off;
    h16* sxT  = (h16*)region;                                         // [T][B][576][512]
    h16* qkvw = (h16*)(region + (size_t)T_DIM * B_DIM * N_DIM * C_DIM * 2);  // [2][3072][512]
    h16* soT  = (h16*)region;                                         // [TB][576][2048]
    off += (size_t)TB_DIM * N_DIM * CV_DIM * 2;              // 75.5 MB region
    // total ~95.2 MB

    // 0) weight splits (swizzled) + scale/bias concat
    split_qkv<<<768, 256, 0, stream>>>(q_w, k_w, v_w, qkvw);
    split_p<<<512, 256, 0, stream>>>(p_w, pw2);
    concat_sb<<<12, 256, 0, stream>>>(q_s, q_b, k_s, k_b, v_s, v_b, scc, bic);

    // 1) LIF on x+pos -> transposed swizzled f16 spikes
    dim3 gl(C_DIM / 64, N_DIM / 64, B_DIM);   // (8,9,8)
    lif_x_T<<<gl, 256, 0, stream>>>(x, pos, sxT);

    // 2) fused q/k/v MFMA GEMM + LIF + pack
    dim3 gq(3072 / 128, 18, B_DIM);    // (24,18,8)
    gemm_qkv_mfma<<<gq, 256, 0, stream>>>(qkvw, sxT, scc, bic, (u32*)qkvb);

    // 3) attention: popcount kv (f16 ints), then MFMA o + LIF -> dense transposed spikes
    kv_pop_kernel<<<TB_DIM * 8, 256, 0, stream>>>(qkvb, kvt);
    dim3 go(NW, 2, B_DIM * 8);         // (9,2,64)
    o_attn_mfma<<<go, 256, 0, stream>>>(qkvb, kvt, soT);

    // 4) output projection (MFMA, 4 tb per block)
    dim3 gp(C_DIM / 128, 18, TB_DIM / 4);  // (4,18,8)
    gemm_p_mfma<<<gp, 256, 0, stream>>>(pw2, soT, p_s, p_b, out);
}